// Round 2
// baseline (1820.612 us; speedup 1.0000x reference)
//
#include <hip/hip_runtime.h>
#include <math.h>

// H=W=56, C=128, WS=7, SS=3, NH=4, P=5, HD=32, NW=64, NTOK=49, N=54, B=64
// x rows: 3141 = 5 + 56*56; window-rows: 4096 = B*NW; tokens/window: 54

// ---------------------------------------------------------------------------
// LN1 + window gather for a chunk of window-rows: xw_c[local_row][128]
// global window-row i: prompt tokens (n<5) from batch i&63;
// spatial from batch i>>6, window i&63, rolled by (-3,-3).
// ---------------------------------------------------------------------------
__global__ __launch_bounds__(256) void ln1_gather(const float* __restrict__ x,
    const float* __restrict__ g, const float* __restrict__ bta,
    float* __restrict__ xw, int i0, int nrows)
{
  int wid = blockIdx.x * 4 + (threadIdx.x >> 6);   // one wave per output row
  if (wid >= nrows) return;
  int lane = threadIdx.x & 63;
  int i = i0 + wid / 54, n = wid % 54;
  int src;
  if (n < 5) {
    src = (i & 63) * 3141 + n;
  } else {
    int b = i >> 6, w = i & 63;
    int t = n - 5;
    int hp = (w >> 3) * 7 + t / 7 + 3; if (hp >= 56) hp -= 56;
    int wp = (w & 7) * 7 + t % 7 + 3;  if (wp >= 56) wp -= 56;
    src = b * 3141 + 5 + hp * 56 + wp;
  }
  const float* xr = x + (size_t)src * 128;
  float v0 = xr[lane], v1 = xr[lane + 64];
  float s = v0 + v1, s2 = v0 * v0 + v1 * v1;
  #pragma unroll
  for (int off = 32; off > 0; off >>= 1) {
    s  += __shfl_xor(s,  off);
    s2 += __shfl_xor(s2, off);
  }
  float mu = s * (1.f / 128.f);
  float var = s2 * (1.f / 128.f) - mu * mu;
  float rs = rsqrtf(var + 1e-5f);
  float* o = xw + (size_t)wid * 128;
  o[lane]      = (v0 - mu) * rs * g[lane]      + bta[lane];
  o[lane + 64] = (v1 - mu) * rs * g[lane + 64] + bta[lane + 64];
}

// ---------------------------------------------------------------------------
// Row LayerNorm (LN2) over contiguous rows
// ---------------------------------------------------------------------------
__global__ __launch_bounds__(256) void ln_rows(const float* __restrict__ xin,
    const float* __restrict__ g, const float* __restrict__ bta,
    float* __restrict__ out, int rows)
{
  int wid = blockIdx.x * 4 + (threadIdx.x >> 6);
  if (wid >= rows) return;
  int lane = threadIdx.x & 63;
  const float* xr = xin + (size_t)wid * 128;
  float v0 = xr[lane], v1 = xr[lane + 64];
  float s = v0 + v1, s2 = v0 * v0 + v1 * v1;
  #pragma unroll
  for (int off = 32; off > 0; off >>= 1) {
    s  += __shfl_xor(s,  off);
    s2 += __shfl_xor(s2, off);
  }
  float mu = s * (1.f / 128.f);
  float var = s2 * (1.f / 128.f) - mu * mu;
  float rs = rsqrtf(var + 1e-5f);
  float* o = out + (size_t)wid * 128;
  o[lane]      = (v0 - mu) * rs * g[lane]      + bta[lane];
  o[lane + 64] = (v1 - mu) * rs * g[lane + 64] + bta[lane + 64];
}

// ---------------------------------------------------------------------------
// fp32 tiled GEMM: C[M,N] = A[M,K] @ W[K,N] + bias.
// EPI 0: none; 1: exact GELU; 2: += R (C==R in-place ok).
// BM=BN=64, BK=32, 256 threads, 4x4/thread. M%64==0, N%64==0, K%32==0.
// ---------------------------------------------------------------------------
template<int EPI>
__global__ __launch_bounds__(256) void gemm_f32(
    const float* __restrict__ A, const float* __restrict__ W,
    const float* __restrict__ bias, float* __restrict__ C,
    const float* __restrict__ R, int M, int N, int K)
{
  __shared__ float As[32][64];  // As[k][m]
  __shared__ float Ws[32][64];  // Ws[k][n]
  const int tid = threadIdx.x;
  const int tx = tid & 15, ty = tid >> 4;
  const int m0 = blockIdx.y * 64, n0 = blockIdx.x * 64;
  float acc[4][4] = {{0.f}};
  for (int k0 = 0; k0 < K; k0 += 32) {
    #pragma unroll
    for (int l = 0; l < 2; ++l) {
      int li = tid + l * 256;
      int row = li >> 3, j = li & 7;
      float4 a = *(const float4*)(A + (size_t)(m0 + row) * K + k0 + j * 4);
      As[j * 4 + 0][row] = a.x; As[j * 4 + 1][row] = a.y;
      As[j * 4 + 2][row] = a.z; As[j * 4 + 3][row] = a.w;
      int kk = li >> 4, f = li & 15;
      *(float4*)(&Ws[kk][f * 4]) = *(const float4*)(W + (size_t)(k0 + kk) * N + n0 + f * 4);
    }
    __syncthreads();
    #pragma unroll
    for (int kk = 0; kk < 32; ++kk) {
      float4 av = *(const float4*)(&As[kk][ty * 4]);
      float4 wv = *(const float4*)(&Ws[kk][tx * 4]);
      float aarr[4] = {av.x, av.y, av.z, av.w};
      float warr[4] = {wv.x, wv.y, wv.z, wv.w};
      #pragma unroll
      for (int a2 = 0; a2 < 4; ++a2)
        #pragma unroll
        for (int b2 = 0; b2 < 4; ++b2)
          acc[a2][b2] = fmaf(aarr[a2], warr[b2], acc[a2][b2]);
    }
    __syncthreads();
  }
  #pragma unroll
  for (int i2 = 0; i2 < 4; ++i2) {
    int row = m0 + ty * 4 + i2;
    float4 v;
    float* vp = &v.x;
    #pragma unroll
    for (int j2 = 0; j2 < 4; ++j2) {
      int col = n0 + tx * 4 + j2;
      float t = acc[i2][j2] + bias[col];
      if (EPI == 1) t = 0.5f * t * (1.f + erff(t * 0.70710678118654752f));
      if (EPI == 2) t += R[(size_t)row * N + col];
      vp[j2] = t;
    }
    *(float4*)(C + (size_t)row * N + n0 + tx * 4) = v;
  }
}

// ---------------------------------------------------------------------------
// Attention: one 64-thread block per (local window-row li, head h).
// qkv row layout: [q(128) | k(128) | v(128)]; N=54, HD=32.
// ---------------------------------------------------------------------------
__global__ __launch_bounds__(64) void attn_kernel(const float* __restrict__ qkv,
    const float* __restrict__ rpb_table, float* __restrict__ attn_out, int i0)
{
  __shared__ float ks[54][32];
  __shared__ float vs[54][32];
  __shared__ float sm[54][56];
  const int blk = blockIdx.x;
  const int li = blk >> 2, h = blk & 3;
  const int i = i0 + li;
  const int w = i & 63, wh = w >> 3, ww = w & 7;
  const int t = threadIdx.x;
  const float* base = qkv + (size_t)li * 54 * 384 + h * 32;
  for (int idx = t; idx < 54 * 8; idx += 64) {
    int n = idx >> 3, d4 = (idx & 7) * 4;
    *(float4*)(&ks[n][d4]) = *(const float4*)(base + (size_t)n * 384 + 128 + d4);
    *(float4*)(&vs[n][d4]) = *(const float4*)(base + (size_t)n * 384 + 256 + d4);
  }
  float q[32];
  if (t < 54) {
    const float* qr = base + (size_t)t * 384;
    #pragma unroll
    for (int d = 0; d < 32; ++d) q[d] = qr[d] * 0.17677669529663689f;
  }
  __syncthreads();
  if (t < 54) {
    int lt = -1;
    if (t >= 5) {
      int tt = t - 5;
      int r = wh * 7 + tt / 7, c = ww * 7 + tt % 7;
      lt = (r < 49 ? 0 : (r < 53 ? 1 : 2)) * 3 + (c < 49 ? 0 : (c < 53 ? 1 : 2));
    }
    float mx = -1e30f;
    for (int m = 0; m < 54; ++m) {
      float s = 0.f;
      #pragma unroll
      for (int d = 0; d < 32; ++d) s = fmaf(q[d], ks[m][d], s);
      if (t >= 5 && m >= 5) {
        int tt = t - 5, mm = m - 5;
        int dh = tt / 7 - mm / 7 + 6, dw = tt % 7 - mm % 7 + 6;
        s += rpb_table[(dh * 13 + dw) * 4 + h];
        int r = wh * 7 + mm / 7, c = ww * 7 + mm % 7;
        int lm = (r < 49 ? 0 : (r < 53 ? 1 : 2)) * 3 + (c < 49 ? 0 : (c < 53 ? 1 : 2));
        if (lm != lt) s += -100.f;
      }
      sm[t][m] = s;
      mx = fmaxf(mx, s);
    }
    float sum = 0.f;
    for (int m = 0; m < 54; ++m) {
      float p = expf(sm[t][m] - mx);
      sm[t][m] = p;
      sum += p;
    }
    float inv = 1.f / sum;
    float acc[32] = {0.f};
    for (int m = 0; m < 54; ++m) {
      float p = sm[t][m] * inv;
      #pragma unroll
      for (int d = 0; d < 32; ++d) acc[d] = fmaf(p, vs[m][d], acc[d]);
    }
    float* orow = attn_out + (size_t)(li * 54 + t) * 128 + h * 32;
    #pragma unroll
    for (int d = 0; d < 32; ++d) orow[d] = acc[d];
  }
}

// ---------------------------------------------------------------------------
// Chunk scatter: spatial tokens -> out (= x + proj), prompt tokens -> pbuf.
// pbuf[i][p][c], i = global window-row. One float4 per thread.
// ---------------------------------------------------------------------------
__global__ __launch_bounds__(256) void scatter_chunk(const float* __restrict__ x,
    const float* __restrict__ proj, float* __restrict__ out,
    float* __restrict__ pbuf, int i0, int nrows)
{
  int idx = blockIdx.x * 256 + threadIdx.x;
  int j = idx & 31;
  int row = idx >> 5;
  if (row >= nrows) return;
  int li = row / 54, n = row % 54;
  int i = i0 + li;
  float4 pv = *(const float4*)(proj + (size_t)row * 128 + j * 4);
  if (n < 5) {
    *(float4*)(pbuf + ((size_t)i * 5 + n) * 128 + j * 4) = pv;
  } else {
    int b = i >> 6, w = i & 63, t = n - 5;
    int r  = (w >> 3) * 7 + t / 7 + 3; if (r  >= 56) r  -= 56;
    int cc = (w & 7)  * 7 + t % 7 + 3; if (cc >= 56) cc -= 56;
    size_t o = ((size_t)b * 3141 + 5 + r * 56 + cc) * 128 + j * 4;
    float4 xv = *(const float4*)(x + o);
    xv.x += pv.x; xv.y += pv.y; xv.z += pv.z; xv.w += pv.w;
    *(float4*)(out + o) = xv;
  }
}

// ---------------------------------------------------------------------------
// Prompt mean over windows + residual: out[b,p] = x[b,p] + mean_w pbuf[w*64+b][p]
// ---------------------------------------------------------------------------
__global__ __launch_bounds__(128) void prompt_reduce(const float* __restrict__ x,
    const float* __restrict__ pbuf, float* __restrict__ out)
{
  int bp = blockIdx.x;   // 64*5
  int b = bp / 5, p = bp % 5;
  int c = threadIdx.x;
  float s = 0.f;
  for (int w = 0; w < 64; ++w)
    s += pbuf[((size_t)(w * 64 + b) * 5 + p) * 128 + c];
  size_t oidx = ((size_t)b * 3141 + p) * 128 + c;
  out[oidx] = x[oidx] + s * (1.f / 64.f);
}

// ---------------------------------------------------------------------------
// Launch: chunked pipeline adapted to ws_size (deterministic).
// ---------------------------------------------------------------------------
extern "C" void kernel_launch(void* const* d_in, const int* in_sizes, int n_in,
                              void* d_out, int out_size, void* d_ws, size_t ws_size,
                              hipStream_t stream) {
  const float* x      = (const float*)d_in[0];
  const float* n1g    = (const float*)d_in[1];
  const float* n1b    = (const float*)d_in[2];
  const float* qkv_w  = (const float*)d_in[3];
  const float* qkv_b  = (const float*)d_in[4];
  const float* proj_w = (const float*)d_in[5];
  const float* proj_b = (const float*)d_in[6];
  const float* rpb    = (const float*)d_in[7];
  const float* n2g    = (const float*)d_in[8];
  const float* n2b    = (const float*)d_in[9];
  const float* fc1w   = (const float*)d_in[10];
  const float* fc1b   = (const float*)d_in[11];
  const float* fc2w   = (const float*)d_in[12];
  const float* fc2b   = (const float*)d_in[13];
  float* out = (float*)d_out;
  char* ws = (char*)d_ws;

  const size_t PBUF_BYTES = (size_t)4096 * 5 * 128 * 4;  // 10.49 MB

  // ---- Phase 1: window-row chunks (LN1 -> QKV -> attn -> proj -> scatter)
  // layout per chunk (R = cw*54 rows):
  //   xw_c  @ 0            R*128*4   (reused as attn_out)
  //   qkv_c @ R*128*4      R*384*4   (reused as proj_c)
  //   pbuf  @ R*512*4      PBUF_BYTES
  int cw = 1024;  // cap footprint ~134MB even for huge ws
  while (cw > 32 && (size_t)cw * 54 * 2048 + PBUF_BYTES > ws_size) cw >>= 1;
  {
    size_t R = (size_t)cw * 54;
    float* xw_c  = (float*)ws;
    float* qkv_c = (float*)(ws + R * 128 * 4);
    float* pbuf  = (float*)(ws + R * 512 * 4);
    for (int i0 = 0; i0 < 4096; i0 += cw) {
      int nr = cw * 54;
      hipLaunchKernelGGL(ln1_gather, dim3((nr + 3) / 4), dim3(256), 0, stream,
                         x, n1g, n1b, xw_c, i0, nr);
      hipLaunchKernelGGL((gemm_f32<0>), dim3(6, nr / 64), dim3(256), 0, stream,
                         xw_c, qkv_w, qkv_b, qkv_c, (const float*)nullptr, nr, 384, 128);
      hipLaunchKernelGGL(attn_kernel, dim3(cw * 4), dim3(64), 0, stream,
                         qkv_c, rpb, xw_c, i0);
      hipLaunchKernelGGL((gemm_f32<0>), dim3(2, nr / 64), dim3(256), 0, stream,
                         xw_c, proj_w, proj_b, qkv_c, (const float*)nullptr, nr, 128, 128);
      hipLaunchKernelGGL(scatter_chunk, dim3((nr * 32 + 255) / 256), dim3(256), 0, stream,
                         x, qkv_c, out, pbuf, i0, nr);
    }
    hipLaunchKernelGGL(prompt_reduce, dim3(320), dim3(128), 0, stream, x, pbuf, out);
  }

  // ---- Phase 2: MLP row chunks (LN2 -> fc1+GELU -> fc2+residual)
  // layout per chunk (Rc = bc*64 rows): ln2_c @ 0 (Rc*128*4), mlp_c @ Rc*512 B (Rc*512*4)
  int bc = 786;  // cap ~129MB
  while (bc > 25 && (size_t)bc * 64 * 2560 > ws_size) bc = (bc + 1) >> 1;
  {
    float* ln2_c = (float*)ws;
    float* mlp_c = (float*)(ws + (size_t)bc * 64 * 512);
    for (int b0 = 0; b0 < 3141; b0 += bc) {
      int nb = (3141 - b0 < bc) ? (3141 - b0) : bc;
      int Rc = nb * 64;
      float* orow = out + (size_t)b0 * 64 * 128;
      hipLaunchKernelGGL(ln_rows, dim3((Rc + 3) / 4), dim3(256), 0, stream,
                         orow, n2g, n2b, ln2_c, Rc);
      hipLaunchKernelGGL((gemm_f32<1>), dim3(8, nb), dim3(256), 0, stream,
                         ln2_c, fc1w, fc1b, mlp_c, (const float*)nullptr, Rc, 512, 128);
      hipLaunchKernelGGL((gemm_f32<2>), dim3(2, nb), dim3(256), 0, stream,
                         mlp_c, fc2w, fc2b, orow, orow, Rc, 128, 512);
    }
  }
  (void)in_sizes; (void)n_in; (void)out_size; (void)ws_size;
}

// Round 3
// 865.266 us; speedup vs baseline: 2.1041x; 2.1041x over previous
//
#include <hip/hip_runtime.h>
#include <hip/hip_bf16.h>
#include <math.h>

// H=W=56, C=128, WS=7, SS=3, NH=4, P=5, HD=32, NW=64, NTOK=49, N=54, B=64
// x rows: 3141 = 5 + 56*56; window-rows: 4096 = B*NW; tokens/window: 54

typedef __attribute__((ext_vector_type(8))) short bf16x8;
typedef __attribute__((ext_vector_type(4))) float f32x4;
typedef __attribute__((ext_vector_type(4))) unsigned short u16x4;

__device__ __forceinline__ float bf2f(unsigned short u) {
  union { unsigned int i; float f; } v; v.i = ((unsigned)u) << 16; return v.f;
}

// ---------------------------------------------------------------------------
// Weight convert: wt[n][k] = bf16(w[k][n])  (transposed, once per launch)
// ---------------------------------------------------------------------------
__global__ __launch_bounds__(256) void convert_wt(const float* __restrict__ w,
    __hip_bfloat16* __restrict__ wt, int K, int N)
{
  int idx = blockIdx.x * 256 + threadIdx.x;
  if (idx >= N * K) return;
  int n = idx / K, k = idx % K;
  wt[idx] = __float2bfloat16(w[(size_t)k * N + n]);
}

// ---------------------------------------------------------------------------
// LN1 + window gather -> xw_c bf16 [nrows][128]
// ---------------------------------------------------------------------------
__global__ __launch_bounds__(256) void ln1_gather(const float* __restrict__ x,
    const float* __restrict__ g, const float* __restrict__ bta,
    __hip_bfloat16* __restrict__ xw, int i0, int nrows)
{
  int wid = blockIdx.x * 4 + (threadIdx.x >> 6);
  if (wid >= nrows) return;
  int lane = threadIdx.x & 63;
  int i = i0 + wid / 54, n = wid % 54;
  int src;
  if (n < 5) {
    src = (i & 63) * 3141 + n;
  } else {
    int b = i >> 6, w = i & 63;
    int t = n - 5;
    int hp = (w >> 3) * 7 + t / 7 + 3; if (hp >= 56) hp -= 56;
    int wp = (w & 7) * 7 + t % 7 + 3;  if (wp >= 56) wp -= 56;
    src = b * 3141 + 5 + hp * 56 + wp;
  }
  const float* xr = x + (size_t)src * 128;
  float v0 = xr[lane], v1 = xr[lane + 64];
  float s = v0 + v1, s2 = v0 * v0 + v1 * v1;
  #pragma unroll
  for (int off = 32; off > 0; off >>= 1) {
    s  += __shfl_xor(s,  off);
    s2 += __shfl_xor(s2, off);
  }
  float mu = s * (1.f / 128.f);
  float var = s2 * (1.f / 128.f) - mu * mu;
  float rs = rsqrtf(var + 1e-5f);
  __hip_bfloat16* o = xw + (size_t)wid * 128;
  o[lane]      = __float2bfloat16((v0 - mu) * rs * g[lane]      + bta[lane]);
  o[lane + 64] = __float2bfloat16((v1 - mu) * rs * g[lane + 64] + bta[lane + 64]);
}

// ---------------------------------------------------------------------------
// LN2 rows: fp32 in -> bf16 out
// ---------------------------------------------------------------------------
__global__ __launch_bounds__(256) void ln_rows(const float* __restrict__ xin,
    const float* __restrict__ g, const float* __restrict__ bta,
    __hip_bfloat16* __restrict__ out, int rows)
{
  int wid = blockIdx.x * 4 + (threadIdx.x >> 6);
  if (wid >= rows) return;
  int lane = threadIdx.x & 63;
  const float* xr = xin + (size_t)wid * 128;
  float v0 = xr[lane], v1 = xr[lane + 64];
  float s = v0 + v1, s2 = v0 * v0 + v1 * v1;
  #pragma unroll
  for (int off = 32; off > 0; off >>= 1) {
    s  += __shfl_xor(s,  off);
    s2 += __shfl_xor(s2, off);
  }
  float mu = s * (1.f / 128.f);
  float var = s2 * (1.f / 128.f) - mu * mu;
  float rs = rsqrtf(var + 1e-5f);
  __hip_bfloat16* o = out + (size_t)wid * 128;
  o[lane]      = __float2bfloat16((v0 - mu) * rs * g[lane]      + bta[lane]);
  o[lane + 64] = __float2bfloat16((v1 - mu) * rs * g[lane + 64] + bta[lane + 64]);
}

// ---------------------------------------------------------------------------
// bf16 MFMA GEMM: C[M,N] = A[M,K] @ Wt[N,K]^T + bias.
// Tile 128x128, 4 waves (64x64 each, 4x4 frags of 16x16x32), BK=64.
// Staging: global_load_lds w16, source pre-swizzled (chunk ^= row&7),
// reads XOR-swizzled ds_read_b128 -> conflict-free.
// A rows up to gridDim.y*128 must be readable (padded alloc); stores guarded
// by Mstore. EPI: 0 none, 1 exact GELU, 2 += Rres. OUTBF: 1 bf16 out, 0 f32.
// ---------------------------------------------------------------------------
template<int EPI, int OUTBF>
__global__ __launch_bounds__(256) void gemm_mfma(
    const __hip_bfloat16* __restrict__ A, const __hip_bfloat16* __restrict__ Wt,
    const float* __restrict__ bias, void* __restrict__ Cout,
    const float* __restrict__ Rres, int Mstore, int N, int K)
{
  __shared__ short As[8192];   // 128 rows x 64 k, 16B-chunk-swizzled
  __shared__ short Ws[8192];   // 128 cols x 64 k
  const int tid = threadIdx.x;
  const int wv = tid >> 6, lane = tid & 63;
  const int m0 = blockIdx.y * 128, n0 = blockIdx.x * 128;
  const int wr = wv >> 1, wc = wv & 1;
  f32x4 acc[4][4] = {};
  const int srow = wv * 8 + (lane >> 3);   // staging row within a 32-row group
  const int schunk = lane & 7;             // 16B chunk within 128B row

  for (int k0 = 0; k0 < K; k0 += 64) {
    #pragma unroll
    for (int i = 0; i < 4; ++i) {
      int row = i * 32 + srow;
      int kk = k0 + ((schunk ^ (row & 7)) << 3);
      const __hip_bfloat16* ga = A  + (size_t)(m0 + row) * K + kk;
      const __hip_bfloat16* gw = Wt + (size_t)(n0 + row) * K + kk;
      __builtin_amdgcn_global_load_lds(
          (const __attribute__((address_space(1))) void*)ga,
          (__attribute__((address_space(3))) void*)(As + i * 2048 + wv * 512),
          16, 0, 0);
      __builtin_amdgcn_global_load_lds(
          (const __attribute__((address_space(1))) void*)gw,
          (__attribute__((address_space(3))) void*)(Ws + i * 2048 + wv * 512),
          16, 0, 0);
    }
    __syncthreads();
    #pragma unroll
    for (int s = 0; s < 2; ++s) {
      bf16x8 af[4], bfr[4];
      #pragma unroll
      for (int mi = 0; mi < 4; ++mi) {
        int r = wr * 64 + mi * 16 + (lane & 15);
        int ch = ((s << 2) + (lane >> 4)) ^ (r & 7);
        af[mi] = *(const bf16x8*)(As + r * 64 + ch * 8);
      }
      #pragma unroll
      for (int ni = 0; ni < 4; ++ni) {
        int r = wc * 64 + ni * 16 + (lane & 15);
        int ch = ((s << 2) + (lane >> 4)) ^ (r & 7);
        bfr[ni] = *(const bf16x8*)(Ws + r * 64 + ch * 8);
      }
      #pragma unroll
      for (int mi = 0; mi < 4; ++mi)
        #pragma unroll
        for (int ni = 0; ni < 4; ++ni)
          acc[mi][ni] = __builtin_amdgcn_mfma_f32_16x16x32_bf16(
              af[mi], bfr[ni], acc[mi][ni], 0, 0, 0);
    }
    __syncthreads();
  }

  // Epilogue. C/D map: col = lane&15, row = (lane>>4)*4 + reg.
  const int cl = lane & 15, rh = lane >> 4;
  #pragma unroll
  for (int mi = 0; mi < 4; ++mi) {
    #pragma unroll
    for (int r = 0; r < 4; ++r) {
      int grow = m0 + wr * 64 + mi * 16 + rh * 4 + r;
      if (grow < Mstore) {
        #pragma unroll
        for (int ni = 0; ni < 4; ++ni) {
          int gcol = n0 + wc * 64 + ni * 16 + cl;
          float t = acc[mi][ni][r] + bias[gcol];
          if (EPI == 1) t = 0.5f * t * (1.f + erff(t * 0.70710678118654752f));
          if (EPI == 2) t += Rres[(size_t)grow * N + gcol];
          if (OUTBF)
            ((__hip_bfloat16*)Cout)[(size_t)grow * N + gcol] = __float2bfloat16(t);
          else
            ((float*)Cout)[(size_t)grow * N + gcol] = t;
        }
      }
    }
  }
}

// ---------------------------------------------------------------------------
// Attention: one 64-thread block per (local window-row li, head h). bf16 qkv.
// ---------------------------------------------------------------------------
__global__ __launch_bounds__(64) void attn_kernel(
    const __hip_bfloat16* __restrict__ qkv, const float* __restrict__ rpb_table,
    __hip_bfloat16* __restrict__ attn_out, int i0)
{
  __shared__ float ks[54][32];
  __shared__ float vs[54][32];
  __shared__ float sm[54][56];
  const int blk = blockIdx.x;
  const int li = blk >> 2, h = blk & 3;
  const int i = i0 + li;
  const int w = i & 63, wh = w >> 3, ww = w & 7;
  const int t = threadIdx.x;
  const unsigned short* base = (const unsigned short*)qkv + (size_t)li * 54 * 384 + h * 32;
  for (int idx = t; idx < 54 * 8; idx += 64) {
    int n = idx >> 3, d4 = (idx & 7) * 4;
    u16x4 kv = *(const u16x4*)(base + (size_t)n * 384 + 128 + d4);
    u16x4 vv = *(const u16x4*)(base + (size_t)n * 384 + 256 + d4);
    #pragma unroll
    for (int j = 0; j < 4; ++j) { ks[n][d4 + j] = bf2f(kv[j]); vs[n][d4 + j] = bf2f(vv[j]); }
  }
  float q[32];
  if (t < 54) {
    const unsigned short* qr = base + (size_t)t * 384;
    #pragma unroll
    for (int d = 0; d < 32; ++d) q[d] = bf2f(qr[d]) * 0.17677669529663689f;
  }
  __syncthreads();
  if (t < 54) {
    int lt = -1;
    if (t >= 5) {
      int tt = t - 5;
      int r = wh * 7 + tt / 7, c = ww * 7 + tt % 7;
      lt = (r < 49 ? 0 : (r < 53 ? 1 : 2)) * 3 + (c < 49 ? 0 : (c < 53 ? 1 : 2));
    }
    float mx = -1e30f;
    for (int m = 0; m < 54; ++m) {
      float s = 0.f;
      #pragma unroll
      for (int d = 0; d < 32; ++d) s = fmaf(q[d], ks[m][d], s);
      if (t >= 5 && m >= 5) {
        int tt = t - 5, mm = m - 5;
        int dh = tt / 7 - mm / 7 + 6, dw = tt % 7 - mm % 7 + 6;
        s += rpb_table[(dh * 13 + dw) * 4 + h];
        int r = wh * 7 + mm / 7, c = ww * 7 + mm % 7;
        int lm = (r < 49 ? 0 : (r < 53 ? 1 : 2)) * 3 + (c < 49 ? 0 : (c < 53 ? 1 : 2));
        if (lm != lt) s += -100.f;
      }
      sm[t][m] = s;
      mx = fmaxf(mx, s);
    }
    float sum = 0.f;
    for (int m = 0; m < 54; ++m) {
      float p = expf(sm[t][m] - mx);
      sm[t][m] = p;
      sum += p;
    }
    float inv = 1.f / sum;
    float acc[32] = {0.f};
    for (int m = 0; m < 54; ++m) {
      float p = sm[t][m] * inv;
      #pragma unroll
      for (int d = 0; d < 32; ++d) acc[d] = fmaf(p, vs[m][d], acc[d]);
    }
    __hip_bfloat16* orow = attn_out + (size_t)(li * 54 + t) * 128 + h * 32;
    #pragma unroll
    for (int d = 0; d < 32; ++d) orow[d] = __float2bfloat16(acc[d]);
  }
}

// ---------------------------------------------------------------------------
// Chunk scatter: spatial -> out (= x + proj), prompt -> pbuf
// ---------------------------------------------------------------------------
__global__ __launch_bounds__(256) void scatter_chunk(const float* __restrict__ x,
    const float* __restrict__ proj, float* __restrict__ out,
    float* __restrict__ pbuf, int i0, int nrows)
{
  int idx = blockIdx.x * 256 + threadIdx.x;
  int j = idx & 31;
  int row = idx >> 5;
  if (row >= nrows) return;
  int li = row / 54, n = row % 54;
  int i = i0 + li;
  float4 pv = *(const float4*)(proj + (size_t)row * 128 + j * 4);
  if (n < 5) {
    *(float4*)(pbuf + ((size_t)i * 5 + n) * 128 + j * 4) = pv;
  } else {
    int b = i >> 6, w = i & 63, t = n - 5;
    int r  = (w >> 3) * 7 + t / 7 + 3; if (r  >= 56) r  -= 56;
    int cc = (w & 7)  * 7 + t % 7 + 3; if (cc >= 56) cc -= 56;
    size_t o = ((size_t)b * 3141 + 5 + r * 56 + cc) * 128 + j * 4;
    float4 xv = *(const float4*)(x + o);
    xv.x += pv.x; xv.y += pv.y; xv.z += pv.z; xv.w += pv.w;
    *(float4*)(out + o) = xv;
  }
}

// ---------------------------------------------------------------------------
// Prompt mean over windows + residual
// ---------------------------------------------------------------------------
__global__ __launch_bounds__(128) void prompt_reduce(const float* __restrict__ x,
    const float* __restrict__ pbuf, float* __restrict__ out)
{
  int bp = blockIdx.x;   // 64*5
  int b = bp / 5, p = bp % 5;
  int c = threadIdx.x;
  float s = 0.f;
  for (int w = 0; w < 64; ++w)
    s += pbuf[((size_t)(w * 64 + b) * 5 + p) * 128 + c];
  size_t oidx = ((size_t)b * 3141 + p) * 128 + c;
  out[oidx] = x[oidx] + s * (1.f / 64.f);
}

// ---------------------------------------------------------------------------
// Launch
// ---------------------------------------------------------------------------
extern "C" void kernel_launch(void* const* d_in, const int* in_sizes, int n_in,
                              void* d_out, int out_size, void* d_ws, size_t ws_size,
                              hipStream_t stream) {
  const float* x      = (const float*)d_in[0];
  const float* n1g    = (const float*)d_in[1];
  const float* n1b    = (const float*)d_in[2];
  const float* qkv_w  = (const float*)d_in[3];
  const float* qkv_b  = (const float*)d_in[4];
  const float* proj_w = (const float*)d_in[5];
  const float* proj_b = (const float*)d_in[6];
  const float* rpb    = (const float*)d_in[7];
  const float* n2g    = (const float*)d_in[8];
  const float* n2b    = (const float*)d_in[9];
  const float* fc1w   = (const float*)d_in[10];
  const float* fc1b   = (const float*)d_in[11];
  const float* fc2w   = (const float*)d_in[12];
  const float* fc2b   = (const float*)d_in[13];
  float* out = (float*)d_out;
  char* ws = (char*)d_ws;

  // ws layout:
  //   [0, 384K)          transposed bf16 weights
  //   [512K, 512K+10.5M) pbuf (phase1) / ln2_c+mlp_c (phase2 reuses from 512K)
  //   [11,010,048, ...)  phase1 chunk buffers
  __hip_bfloat16* wbuf = (__hip_bfloat16*)ws;
  __hip_bfloat16* w_qkv = wbuf;                 // [384][128]
  __hip_bfloat16* w_prj = wbuf + 49152;         // [128][128]
  __hip_bfloat16* w_fc1 = wbuf + 65536;         // [512][128]
  __hip_bfloat16* w_fc2 = wbuf + 131072;        // [128][512]
  hipLaunchKernelGGL(convert_wt, dim3(192), dim3(256), 0, stream, qkv_w, w_qkv, 128, 384);
  hipLaunchKernelGGL(convert_wt, dim3(64),  dim3(256), 0, stream, proj_w, w_prj, 128, 128);
  hipLaunchKernelGGL(convert_wt, dim3(256), dim3(256), 0, stream, fc1w,  w_fc1, 128, 512);
  hipLaunchKernelGGL(convert_wt, dim3(256), dim3(256), 0, stream, fc2w,  w_fc2, 512, 128);

  const size_t CHUNK_BASE = 11010048ULL;
  float* pbuf = (float*)(ws + 524288);

  // ---- Phase 1: LN1 -> QKV -> attn -> proj -> scatter, chunked over window-rows
  int cw = 2048;
  while (cw > 64 && CHUNK_BASE + (size_t)cw * 54 * 1024 > ws_size) cw >>= 1;
  {
    size_t R = (size_t)cw * 54;
    __hip_bfloat16* xw_c  = (__hip_bfloat16*)(ws + CHUNK_BASE);
    __hip_bfloat16* qkv_c = (__hip_bfloat16*)(ws + CHUNK_BASE + R * 256);
    float* proj_c = (float*)qkv_c;
    for (int i0 = 0; i0 < 4096; i0 += cw) {
      int nr = cw * 54;
      hipLaunchKernelGGL(ln1_gather, dim3((nr + 3) / 4), dim3(256), 0, stream,
                         x, n1g, n1b, xw_c, i0, nr);
      hipLaunchKernelGGL((gemm_mfma<0, 1>), dim3(3, nr / 128), dim3(256), 0, stream,
                         xw_c, w_qkv, qkv_b, qkv_c, (const float*)nullptr, nr, 384, 128);
      hipLaunchKernelGGL(attn_kernel, dim3(cw * 4), dim3(64), 0, stream,
                         qkv_c, rpb, xw_c, i0);
      hipLaunchKernelGGL((gemm_mfma<0, 0>), dim3(1, nr / 128), dim3(256), 0, stream,
                         xw_c, w_prj, proj_b, proj_c, (const float*)nullptr, nr, 128, 128);
      hipLaunchKernelGGL(scatter_chunk, dim3((nr * 32 + 255) / 256), dim3(256), 0, stream,
                         x, proj_c, out, pbuf, i0, nr);
    }
    hipLaunchKernelGGL(prompt_reduce, dim3(320), dim3(128), 0, stream, x, pbuf, out);
  }

  // ---- Phase 2: LN2 -> fc1+GELU -> fc2+residual, chunked over 64-row blocks
  int bc = 1571;
  while (bc > 49 && 524288ULL + ((size_t)bc * 64 + 128) * 1280 > ws_size) bc = (bc + 1) >> 1;
  {
    size_t bufrows = (size_t)bc * 64 + 128;
    __hip_bfloat16* ln2_c = (__hip_bfloat16*)(ws + 524288);
    __hip_bfloat16* mlp_c = ln2_c + bufrows * 128;
    for (int b0 = 0; b0 < 3141; b0 += bc) {
      int nb = (3141 - b0 < bc) ? (3141 - b0) : bc;
      int Rc = nb * 64;
      int Mp = (Rc + 127) & ~127;
      float* orow = out + (size_t)b0 * 64 * 128;
      hipLaunchKernelGGL(ln_rows, dim3((Rc + 3) / 4), dim3(256), 0, stream,
                         orow, n2g, n2b, ln2_c, Rc);
      hipLaunchKernelGGL((gemm_mfma<1, 1>), dim3(4, Mp / 128), dim3(256), 0, stream,
                         ln2_c, w_fc1, fc1b, mlp_c, (const float*)nullptr, Rc, 512, 128);
      hipLaunchKernelGGL((gemm_mfma<2, 0>), dim3(1, Mp / 128), dim3(256), 0, stream,
                         mlp_c, w_fc2, fc2b, orow, orow, Rc, 128, 512);
    }
  }
  (void)in_sizes; (void)n_in; (void)out_size; (void)ws_size;
}

// Round 4
// 597.954 us; speedup vs baseline: 3.0447x; 1.4470x over previous
//
#include <hip/hip_runtime.h>
#include <hip/hip_bf16.h>
#include <math.h>

// H=W=56, C=128, WS=7, SS=3, NH=4, P=5, HD=32, NW=64, NTOK=49, N=54, B=64
// x rows: 3141 = 5 + 56*56; window-rows: 4096 = B*NW; tokens/window: 54

typedef __attribute__((ext_vector_type(8))) short bf16x8;
typedef __attribute__((ext_vector_type(4))) float f32x4;
typedef __attribute__((ext_vector_type(4))) unsigned short u16x4;

__device__ __forceinline__ float bf2f(unsigned short u) {
  union { unsigned int i; float f; } v; v.i = ((unsigned)u) << 16; return v.f;
}
__device__ __forceinline__ unsigned short f2b(float f) {
  __hip_bfloat16 b = __float2bfloat16(f);
  return *reinterpret_cast<unsigned short*>(&b);
}

// ---------------------------------------------------------------------------
// Weight convert: wt[n][k] = bf16(w[k][n])
// ---------------------------------------------------------------------------
__global__ __launch_bounds__(256) void convert_wt(const float* __restrict__ w,
    __hip_bfloat16* __restrict__ wt, int K, int N)
{
  int idx = blockIdx.x * 256 + threadIdx.x;
  if (idx >= N * K) return;
  int n = idx / K, k = idx % K;
  wt[idx] = __float2bfloat16(w[(size_t)k * N + n]);
}

// ---------------------------------------------------------------------------
// Bias table gen (once): bias2[w][h][q][k] bf16, exp2-domain.
// k>=54 -> -inf (handles MFMA padding); includes rpb + shift mask.
// ---------------------------------------------------------------------------
__global__ __launch_bounds__(256) void bias_gen(const float* __restrict__ rpb,
    __hip_bfloat16* __restrict__ tab)
{
  int w = blockIdx.x >> 2, h = blockIdx.x & 3;
  int wh = w >> 3, ww = w & 7;
  #pragma unroll
  for (int e = 0; e < 16; ++e) {
    int fi = e * 256 + threadIdx.x;         // 4096 entries
    int q = fi >> 6, k = fi & 63;
    float v;
    if (k >= 54) {
      v = -INFINITY;
    } else {
      v = 0.f;
      if (q >= 5 && q < 54 && k >= 5) {
        int tq = q - 5, tk = k - 5;
        int aq = tq / 7, bq_ = tq % 7, ak = tk / 7, bk = tk % 7;
        int dh = aq - ak + 6, dw = bq_ - bk + 6;
        v = rpb[(dh * 13 + dw) * 4 + h];
        int rq = wh * 7 + aq, cq = ww * 7 + bq_;
        int rk = wh * 7 + ak, ck = ww * 7 + bk;
        int zq = (rq < 49 ? 0 : (rq < 53 ? 1 : 2)) * 3 + (cq < 49 ? 0 : (cq < 53 ? 1 : 2));
        int zk = (rk < 49 ? 0 : (rk < 53 ? 1 : 2)) * 3 + (ck < 49 ? 0 : (ck < 53 ? 1 : 2));
        if (zq != zk) v += -100.f;
      }
      v *= 1.44269504088896f;               // exp2 domain
    }
    tab[((size_t)blockIdx.x << 12) + fi] = __float2bfloat16(v);
  }
}

// ---------------------------------------------------------------------------
// LN1 + window gather -> xw_c bf16
// ---------------------------------------------------------------------------
__global__ __launch_bounds__(256) void ln1_gather(const float* __restrict__ x,
    const float* __restrict__ g, const float* __restrict__ bta,
    __hip_bfloat16* __restrict__ xw, int i0, int nrows)
{
  int wid = blockIdx.x * 4 + (threadIdx.x >> 6);
  if (wid >= nrows) return;
  int lane = threadIdx.x & 63;
  int i = i0 + wid / 54, n = wid % 54;
  int src;
  if (n < 5) {
    src = (i & 63) * 3141 + n;
  } else {
    int b = i >> 6, w = i & 63;
    int t = n - 5;
    int hp = (w >> 3) * 7 + t / 7 + 3; if (hp >= 56) hp -= 56;
    int wp = (w & 7) * 7 + t % 7 + 3;  if (wp >= 56) wp -= 56;
    src = b * 3141 + 5 + hp * 56 + wp;
  }
  const float* xr = x + (size_t)src * 128;
  float v0 = xr[lane], v1 = xr[lane + 64];
  float s = v0 + v1, s2 = v0 * v0 + v1 * v1;
  #pragma unroll
  for (int off = 32; off > 0; off >>= 1) {
    s  += __shfl_xor(s,  off);
    s2 += __shfl_xor(s2, off);
  }
  float mu = s * (1.f / 128.f);
  float var = s2 * (1.f / 128.f) - mu * mu;
  float rs = rsqrtf(var + 1e-5f);
  __hip_bfloat16* o = xw + (size_t)wid * 128;
  o[lane]      = __float2bfloat16((v0 - mu) * rs * g[lane]      + bta[lane]);
  o[lane + 64] = __float2bfloat16((v1 - mu) * rs * g[lane + 64] + bta[lane + 64]);
}

// ---------------------------------------------------------------------------
// LN2 rows: fp32 in -> bf16 out
// ---------------------------------------------------------------------------
__global__ __launch_bounds__(256) void ln_rows(const float* __restrict__ xin,
    const float* __restrict__ g, const float* __restrict__ bta,
    __hip_bfloat16* __restrict__ out, int rows)
{
  int wid = blockIdx.x * 4 + (threadIdx.x >> 6);
  if (wid >= rows) return;
  int lane = threadIdx.x & 63;
  const float* xr = xin + (size_t)wid * 128;
  float v0 = xr[lane], v1 = xr[lane + 64];
  float s = v0 + v1, s2 = v0 * v0 + v1 * v1;
  #pragma unroll
  for (int off = 32; off > 0; off >>= 1) {
    s  += __shfl_xor(s,  off);
    s2 += __shfl_xor(s2, off);
  }
  float mu = s * (1.f / 128.f);
  float var = s2 * (1.f / 128.f) - mu * mu;
  float rs = rsqrtf(var + 1e-5f);
  __hip_bfloat16* o = out + (size_t)wid * 128;
  o[lane]      = __float2bfloat16((v0 - mu) * rs * g[lane]      + bta[lane]);
  o[lane + 64] = __float2bfloat16((v1 - mu) * rs * g[lane + 64] + bta[lane + 64]);
}

// ---------------------------------------------------------------------------
// bf16 MFMA GEMM (unchanged from round 2): C = A @ Wt^T + bias
// ---------------------------------------------------------------------------
template<int EPI, int OUTBF>
__global__ __launch_bounds__(256) void gemm_mfma(
    const __hip_bfloat16* __restrict__ A, const __hip_bfloat16* __restrict__ Wt,
    const float* __restrict__ bias, void* __restrict__ Cout,
    const float* __restrict__ Rres, int Mstore, int N, int K)
{
  __shared__ short As[8192];
  __shared__ short Ws[8192];
  const int tid = threadIdx.x;
  const int wv = tid >> 6, lane = tid & 63;
  const int m0 = blockIdx.y * 128, n0 = blockIdx.x * 128;
  const int wr = wv >> 1, wc = wv & 1;
  f32x4 acc[4][4] = {};
  const int srow = wv * 8 + (lane >> 3);
  const int schunk = lane & 7;

  for (int k0 = 0; k0 < K; k0 += 64) {
    #pragma unroll
    for (int i = 0; i < 4; ++i) {
      int row = i * 32 + srow;
      int kk = k0 + ((schunk ^ (row & 7)) << 3);
      const __hip_bfloat16* ga = A  + (size_t)(m0 + row) * K + kk;
      const __hip_bfloat16* gw = Wt + (size_t)(n0 + row) * K + kk;
      __builtin_amdgcn_global_load_lds(
          (const __attribute__((address_space(1))) void*)ga,
          (__attribute__((address_space(3))) void*)(As + i * 2048 + wv * 512),
          16, 0, 0);
      __builtin_amdgcn_global_load_lds(
          (const __attribute__((address_space(1))) void*)gw,
          (__attribute__((address_space(3))) void*)(Ws + i * 2048 + wv * 512),
          16, 0, 0);
    }
    __syncthreads();
    #pragma unroll
    for (int s = 0; s < 2; ++s) {
      bf16x8 af[4], bfr[4];
      #pragma unroll
      for (int mi = 0; mi < 4; ++mi) {
        int r = wr * 64 + mi * 16 + (lane & 15);
        int ch = ((s << 2) + (lane >> 4)) ^ (r & 7);
        af[mi] = *(const bf16x8*)(As + r * 64 + ch * 8);
      }
      #pragma unroll
      for (int ni = 0; ni < 4; ++ni) {
        int r = wc * 64 + ni * 16 + (lane & 15);
        int ch = ((s << 2) + (lane >> 4)) ^ (r & 7);
        bfr[ni] = *(const bf16x8*)(Ws + r * 64 + ch * 8);
      }
      #pragma unroll
      for (int mi = 0; mi < 4; ++mi)
        #pragma unroll
        for (int ni = 0; ni < 4; ++ni)
          acc[mi][ni] = __builtin_amdgcn_mfma_f32_16x16x32_bf16(
              af[mi], bfr[ni], acc[mi][ni], 0, 0, 0);
    }
    __syncthreads();
  }
  const int cl = lane & 15, rh = lane >> 4;
  #pragma unroll
  for (int mi = 0; mi < 4; ++mi) {
    #pragma unroll
    for (int r = 0; r < 4; ++r) {
      int grow = m0 + wr * 64 + mi * 16 + rh * 4 + r;
      if (grow < Mstore) {
        #pragma unroll
        for (int ni = 0; ni < 4; ++ni) {
          int gcol = n0 + wc * 64 + ni * 16 + cl;
          float t = acc[mi][ni][r] + bias[gcol];
          if (EPI == 1) t = 0.5f * t * (1.f + erff(t * 0.70710678118654752f));
          if (EPI == 2) t += Rres[(size_t)grow * N + gcol];
          if (OUTBF)
            ((__hip_bfloat16*)Cout)[(size_t)grow * N + gcol] = __float2bfloat16(t);
          else
            ((float*)Cout)[(size_t)grow * N + gcol] = t;
        }
      }
    }
  }
}

// ---------------------------------------------------------------------------
// MFMA attention: block = one window-row i, wave = one head. Barrier-free.
// LDS per head (6144 shorts): Qh[64][32] @0, Kh @2048, Vh @4096.
// Ps[64][64] overlays Qh+Kh after QK^T. All tiles XOR-chunk-swizzled.
// ---------------------------------------------------------------------------
__global__ __launch_bounds__(256) void attn_mfma(
    const __hip_bfloat16* __restrict__ qkv,
    const __hip_bfloat16* __restrict__ bias_tab,
    __hip_bfloat16* __restrict__ attn_out, int i0)
{
  __shared__ short lds[24576];
  const int tid = threadIdx.x;
  const int h = tid >> 6, lane = tid & 63;
  const int li = blockIdx.x;
  const int w = (i0 + li) & 63;
  const int c = lane & 15, g = lane >> 4;
  short* Lh = lds + h * 6144;
  const unsigned short* qk = (const unsigned short*)qkv;

  // ---- stage Q,K,V (own head region only; no cross-wave deps)
  #pragma unroll
  for (int m = 0; m < 3; ++m) {
    #pragma unroll
    for (int t = 0; t < 4; ++t) {
      int tok = t * 16 + (lane >> 2);
      int swz = (m == 2) ? ((tok >> 3) & 3) : ((tok >> 1) & 3);
      int ch = (lane & 3) ^ swz;
      const unsigned short* ga = qk + (size_t)(li * 54 + tok) * 384 + m * 128 + h * 32 + ch * 8;
      __builtin_amdgcn_global_load_lds(
          (const __attribute__((address_space(1))) void*)ga,
          (__attribute__((address_space(3))) void*)(Lh + m * 2048 + t * 512),
          16, 0, 0);
    }
  }

  // ---- bias quads (global L2, issued early to hide latency)
  const unsigned short* bt = (const unsigned short*)bias_tab + ((size_t)(w * 4 + h) << 12);
  u16x4 bb[4][4];
  #pragma unroll
  for (int ni = 0; ni < 4; ++ni)
    #pragma unroll
    for (int mi = 0; mi < 4; ++mi)
      bb[ni][mi] = *(const u16x4*)(bt + (ni * 16 + c) * 64 + mi * 16 + g * 4);

  asm volatile("s_waitcnt vmcnt(0)" ::: "memory");
  __builtin_amdgcn_sched_barrier(0);

  // ---- QK^T (swapped): acc[mi][ni] = S^T tile, k = mi*16+g*4+r, q = ni*16+c
  bf16x8 af[4], bq[4];
  #pragma unroll
  for (int mi = 0; mi < 4; ++mi) {
    int tok = mi * 16 + c;
    af[mi] = *(const bf16x8*)(Lh + 2048 + tok * 32 + ((g ^ ((tok >> 1) & 3)) << 3));
  }
  #pragma unroll
  for (int ni = 0; ni < 4; ++ni) {
    int q = ni * 16 + c;
    bq[ni] = *(const bf16x8*)(Lh + q * 32 + ((g ^ ((q >> 1) & 3)) << 3));
  }
  f32x4 acc[4][4] = {};
  #pragma unroll
  for (int mi = 0; mi < 4; ++mi)
    #pragma unroll
    for (int ni = 0; ni < 4; ++ni)
      acc[mi][ni] = __builtin_amdgcn_mfma_f32_16x16x32_bf16(af[mi], bq[ni], acc[mi][ni], 0, 0, 0);

  // ---- scale + bias (exp2 domain)
  const float SC = 0.17677669529663689f * 1.44269504088896f;
  #pragma unroll
  for (int ni = 0; ni < 4; ++ni)
    #pragma unroll
    for (int mi = 0; mi < 4; ++mi)
      #pragma unroll
      for (int r = 0; r < 4; ++r)
        acc[mi][ni][r] = acc[mi][ni][r] * SC + bf2f(bb[ni][mi][r]);

  // ---- softmax over k (16 regs + shfl over g), write P to Ps (overlay Q/K)
  #pragma unroll
  for (int ni = 0; ni < 4; ++ni) {
    float m2 = -3.0e38f;
    #pragma unroll
    for (int mi = 0; mi < 4; ++mi)
      #pragma unroll
      for (int r = 0; r < 4; ++r)
        m2 = fmaxf(m2, acc[mi][ni][r]);
    m2 = fmaxf(m2, __shfl_xor(m2, 16, 64));
    m2 = fmaxf(m2, __shfl_xor(m2, 32, 64));
    float sm = 0.f;
    #pragma unroll
    for (int mi = 0; mi < 4; ++mi)
      #pragma unroll
      for (int r = 0; r < 4; ++r) {
        float p = exp2f(acc[mi][ni][r] - m2);
        acc[mi][ni][r] = p;
        sm += p;
      }
    sm += __shfl_xor(sm, 16, 64);
    sm += __shfl_xor(sm, 32, 64);
    float inv = 1.0f / sm;
    int q = ni * 16 + c;
    #pragma unroll
    for (int mi = 0; mi < 4; ++mi) {
      u16x4 pw;
      #pragma unroll
      for (int r = 0; r < 4; ++r) pw[r] = f2b(acc[mi][ni][r] * inv);
      int chp = (mi * 2 + (g >> 1)) ^ (q & 7);
      *(u16x4*)(Lh + q * 64 + chp * 8 + (g & 1) * 4) = pw;
    }
  }

  // ---- PV: out[q][d] = P @ V
  f32x4 acc2[4][2] = {};
  #pragma unroll
  for (int ks = 0; ks < 2; ++ks) {
    bf16x8 pa[4];
    #pragma unroll
    for (int qi = 0; qi < 4; ++qi) {
      int q = qi * 16 + c;
      int chk = (ks * 4 + g) ^ (q & 7);
      pa[qi] = *(const bf16x8*)(Lh + q * 64 + chk * 8);
    }
    bf16x8 vb[2];
    #pragma unroll
    for (int di = 0; di < 2; ++di) {
      #pragma unroll
      for (int j = 0; j < 8; ++j) {
        int k = ks * 32 + g * 8 + j;
        int chv = ((di * 2 + (c >> 3)) ^ g);
        vb[di][j] = Lh[4096 + k * 32 + chv * 8 + (c & 7)];
      }
    }
    #pragma unroll
    for (int qi = 0; qi < 4; ++qi)
      #pragma unroll
      for (int di = 0; di < 2; ++di)
        acc2[qi][di] = __builtin_amdgcn_mfma_f32_16x16x32_bf16(pa[qi], vb[di], acc2[qi][di], 0, 0, 0);
  }

  // ---- store (rows q<54)
  #pragma unroll
  for (int qi = 0; qi < 4; ++qi) {
    #pragma unroll
    for (int r = 0; r < 4; ++r) {
      int q = qi * 16 + g * 4 + r;
      if (q < 54) {
        __hip_bfloat16* orow = attn_out + (size_t)(li * 54 + q) * 128 + h * 32;
        #pragma unroll
        for (int di = 0; di < 2; ++di)
          orow[di * 16 + c] = __float2bfloat16(acc2[qi][di][r]);
      }
    }
  }
}

// ---------------------------------------------------------------------------
// Chunk scatter: spatial -> out (= x + proj), prompt -> pbuf
// ---------------------------------------------------------------------------
__global__ __launch_bounds__(256) void scatter_chunk(const float* __restrict__ x,
    const float* __restrict__ proj, float* __restrict__ out,
    float* __restrict__ pbuf, int i0, int nrows)
{
  int idx = blockIdx.x * 256 + threadIdx.x;
  int j = idx & 31;
  int row = idx >> 5;
  if (row >= nrows) return;
  int li = row / 54, n = row % 54;
  int i = i0 + li;
  float4 pv = *(const float4*)(proj + (size_t)row * 128 + j * 4);
  if (n < 5) {
    *(float4*)(pbuf + ((size_t)i * 5 + n) * 128 + j * 4) = pv;
  } else {
    int b = i >> 6, w = i & 63, t = n - 5;
    int r  = (w >> 3) * 7 + t / 7 + 3; if (r  >= 56) r  -= 56;
    int cc = (w & 7)  * 7 + t % 7 + 3; if (cc >= 56) cc -= 56;
    size_t o = ((size_t)b * 3141 + 5 + r * 56 + cc) * 128 + j * 4;
    float4 xv = *(const float4*)(x + o);
    xv.x += pv.x; xv.y += pv.y; xv.z += pv.z; xv.w += pv.w;
    *(float4*)(out + o) = xv;
  }
}

// ---------------------------------------------------------------------------
// Prompt mean over windows + residual
// ---------------------------------------------------------------------------
__global__ __launch_bounds__(128) void prompt_reduce(const float* __restrict__ x,
    const float* __restrict__ pbuf, float* __restrict__ out)
{
  int bp = blockIdx.x;
  int b = bp / 5, p = bp % 5;
  int c = threadIdx.x;
  float s = 0.f;
  for (int w = 0; w < 64; ++w)
    s += pbuf[((size_t)(w * 64 + b) * 5 + p) * 128 + c];
  size_t oidx = ((size_t)b * 3141 + p) * 128 + c;
  out[oidx] = x[oidx] + s * (1.f / 64.f);
}

// ---------------------------------------------------------------------------
// Launch
// ---------------------------------------------------------------------------
extern "C" void kernel_launch(void* const* d_in, const int* in_sizes, int n_in,
                              void* d_out, int out_size, void* d_ws, size_t ws_size,
                              hipStream_t stream) {
  const float* x      = (const float*)d_in[0];
  const float* n1g    = (const float*)d_in[1];
  const float* n1b    = (const float*)d_in[2];
  const float* qkv_w  = (const float*)d_in[3];
  const float* qkv_b  = (const float*)d_in[4];
  const float* proj_w = (const float*)d_in[5];
  const float* proj_b = (const float*)d_in[6];
  const float* rpb    = (const float*)d_in[7];
  const float* n2g    = (const float*)d_in[8];
  const float* n2b    = (const float*)d_in[9];
  const float* fc1w   = (const float*)d_in[10];
  const float* fc1b   = (const float*)d_in[11];
  const float* fc2w   = (const float*)d_in[12];
  const float* fc2b   = (const float*)d_in[13];
  float* out = (float*)d_out;
  char* ws = (char*)d_ws;

  // ws layout (bytes):
  //   [0, 393216)          bf16 weights (transposed)
  //   [393216, 2490368)    bias table 64*4*64*64 bf16 = 2 MB
  //   [2490368, 12976128)  pbuf (phase1) / phase2 chunk buffers
  //   [12976128, ...)      phase1 chunk buffers
  __hip_bfloat16* wbuf = (__hip_bfloat16*)ws;
  __hip_bfloat16* w_qkv = wbuf;
  __hip_bfloat16* w_prj = wbuf + 49152;
  __hip_bfloat16* w_fc1 = wbuf + 65536;
  __hip_bfloat16* w_fc2 = wbuf + 131072;
  __hip_bfloat16* bias_tab = (__hip_bfloat16*)(ws + 393216);
  float* pbuf = (float*)(ws + 2490368);
  const size_t CHUNK_BASE = 12976128ULL;

  hipLaunchKernelGGL(convert_wt, dim3(192), dim3(256), 0, stream, qkv_w, w_qkv, 128, 384);
  hipLaunchKernelGGL(convert_wt, dim3(64),  dim3(256), 0, stream, proj_w, w_prj, 128, 128);
  hipLaunchKernelGGL(convert_wt, dim3(256), dim3(256), 0, stream, fc1w,  w_fc1, 128, 512);
  hipLaunchKernelGGL(convert_wt, dim3(256), dim3(256), 0, stream, fc2w,  w_fc2, 512, 128);
  hipLaunchKernelGGL(bias_gen, dim3(256), dim3(256), 0, stream, rpb, bias_tab);

  // ---- Phase 1: LN1 -> QKV -> attn(MFMA) -> proj -> scatter
  int cw = 2048;
  while (cw > 64 && CHUNK_BASE + (size_t)cw * 54 * 1024 + 8192 > ws_size) cw >>= 1;
  {
    size_t R = (size_t)cw * 54;
    __hip_bfloat16* xw_c  = (__hip_bfloat16*)(ws + CHUNK_BASE);
    __hip_bfloat16* qkv_c = (__hip_bfloat16*)(ws + CHUNK_BASE + R * 256);
    float* proj_c = (float*)qkv_c;
    for (int i0 = 0; i0 < 4096; i0 += cw) {
      int nr = cw * 54;
      hipLaunchKernelGGL(ln1_gather, dim3((nr + 3) / 4), dim3(256), 0, stream,
                         x, n1g, n1b, xw_c, i0, nr);
      hipLaunchKernelGGL((gemm_mfma<0, 1>), dim3(3, nr / 128), dim3(256), 0, stream,
                         xw_c, w_qkv, qkv_b, qkv_c, (const float*)nullptr, nr, 384, 128);
      hipLaunchKernelGGL(attn_mfma, dim3(cw), dim3(256), 0, stream,
                         qkv_c, bias_tab, xw_c, i0);
      hipLaunchKernelGGL((gemm_mfma<0, 0>), dim3(1, nr / 128), dim3(256), 0, stream,
                         xw_c, w_prj, proj_b, proj_c, (const float*)nullptr, nr, 128, 128);
      hipLaunchKernelGGL(scatter_chunk, dim3((nr * 32 + 255) / 256), dim3(256), 0, stream,
                         x, proj_c, out, pbuf, i0, nr);
    }
    hipLaunchKernelGGL(prompt_reduce, dim3(320), dim3(128), 0, stream, x, pbuf, out);
  }

  // ---- Phase 2: LN2 -> fc1+GELU -> fc2+residual
  const size_t P2_BASE = 2490368ULL;
  int bc = 1571;
  while (bc > 49 && P2_BASE + ((size_t)bc * 64 + 128) * 1280 > ws_size) bc = (bc + 1) >> 1;
  {
    size_t bufrows = (size_t)bc * 64 + 128;
    __hip_bfloat16* ln2_c = (__hip_bfloat16*)(ws + P2_BASE);
    __hip_bfloat16* mlp_c = ln2_c + bufrows * 128;
    for (int b0 = 0; b0 < 3141; b0 += bc) {
      int nb = (3141 - b0 < bc) ? (3141 - b0) : bc;
      int Rc = nb * 64;
      int Mp = (Rc + 127) & ~127;
      float* orow = out + (size_t)b0 * 64 * 128;
      hipLaunchKernelGGL(ln_rows, dim3((Rc + 3) / 4), dim3(256), 0, stream,
                         orow, n2g, n2b, ln2_c, Rc);
      hipLaunchKernelGGL((gemm_mfma<1, 1>), dim3(4, Mp / 128), dim3(256), 0, stream,
                         ln2_c, w_fc1, fc1b, mlp_c, (const float*)nullptr, Rc, 512, 128);
      hipLaunchKernelGGL((gemm_mfma<2, 0>), dim3(1, Mp / 128), dim3(256), 0, stream,
                         mlp_c, w_fc2, fc2b, orow, orow, Rc, 128, 512);
    }
  }
  (void)in_sizes; (void)n_in; (void)out_size; (void)ws_size;
}

// Round 5
// 484.432 us; speedup vs baseline: 3.7582x; 1.2343x over previous
//
#include <hip/hip_runtime.h>
#include <hip/hip_bf16.h>
#include <math.h>

// H=W=56, C=128, WS=7, SS=3, NH=4, P=5, HD=32, NW=64, NTOK=49, N=54, B=64
// x rows: 3141 = 5 + 56*56; window-rows: 4096 = B*NW; tokens/window: 54

typedef __attribute__((ext_vector_type(8))) short bf16x8;
typedef __attribute__((ext_vector_type(4))) float f32x4;
typedef __attribute__((ext_vector_type(4))) unsigned short u16x4;

__device__ __forceinline__ float bf2f(unsigned short u) {
  union { unsigned int i; float f; } v; v.i = ((unsigned)u) << 16; return v.f;
}
__device__ __forceinline__ unsigned short f2b(float f) {
  __hip_bfloat16 b = __float2bfloat16(f);
  return *reinterpret_cast<unsigned short*>(&b);
}

// ---------------------------------------------------------------------------
// Weight convert: wt[n][k] = bf16(w[k][n])
// ---------------------------------------------------------------------------
__global__ __launch_bounds__(256) void convert_wt(const float* __restrict__ w,
    __hip_bfloat16* __restrict__ wt, int K, int N)
{
  int idx = blockIdx.x * 256 + threadIdx.x;
  if (idx >= N * K) return;
  int n = idx / K, k = idx % K;
  wt[idx] = __float2bfloat16(w[(size_t)k * N + n]);
}

// ---------------------------------------------------------------------------
// Bias table gen (once): bias2[w][h][q][k] bf16, exp2-domain; k>=54 -> -inf
// ---------------------------------------------------------------------------
__global__ __launch_bounds__(256) void bias_gen(const float* __restrict__ rpb,
    __hip_bfloat16* __restrict__ tab)
{
  int w = blockIdx.x >> 2, h = blockIdx.x & 3;
  int wh = w >> 3, ww = w & 7;
  #pragma unroll
  for (int e = 0; e < 16; ++e) {
    int fi = e * 256 + threadIdx.x;
    int q = fi >> 6, k = fi & 63;
    float v;
    if (k >= 54) {
      v = -INFINITY;
    } else {
      v = 0.f;
      if (q >= 5 && q < 54 && k >= 5) {
        int tq = q - 5, tk = k - 5;
        int aq = tq / 7, bq_ = tq % 7, ak = tk / 7, bk = tk % 7;
        int dh = aq - ak + 6, dw = bq_ - bk + 6;
        v = rpb[(dh * 13 + dw) * 4 + h];
        int rq = wh * 7 + aq, cq = ww * 7 + bq_;
        int rk = wh * 7 + ak, ck = ww * 7 + bk;
        int zq = (rq < 49 ? 0 : (rq < 53 ? 1 : 2)) * 3 + (cq < 49 ? 0 : (cq < 53 ? 1 : 2));
        int zk = (rk < 49 ? 0 : (rk < 53 ? 1 : 2)) * 3 + (ck < 49 ? 0 : (ck < 53 ? 1 : 2));
        if (zq != zk) v += -100.f;
      }
      v *= 1.44269504088896f;
    }
    tab[((size_t)blockIdx.x << 12) + fi] = __float2bfloat16(v);
  }
}

// ---------------------------------------------------------------------------
// LN1 + window gather -> xw_c bf16
// ---------------------------------------------------------------------------
__global__ __launch_bounds__(256) void ln1_gather(const float* __restrict__ x,
    const float* __restrict__ g, const float* __restrict__ bta,
    __hip_bfloat16* __restrict__ xw, int i0, int nrows)
{
  int wid = blockIdx.x * 4 + (threadIdx.x >> 6);
  if (wid >= nrows) return;
  int lane = threadIdx.x & 63;
  int i = i0 + wid / 54, n = wid % 54;
  int src;
  if (n < 5) {
    src = (i & 63) * 3141 + n;
  } else {
    int b = i >> 6, w = i & 63;
    int t = n - 5;
    int hp = (w >> 3) * 7 + t / 7 + 3; if (hp >= 56) hp -= 56;
    int wp = (w & 7) * 7 + t % 7 + 3;  if (wp >= 56) wp -= 56;
    src = b * 3141 + 5 + hp * 56 + wp;
  }
  const float* xr = x + (size_t)src * 128;
  float v0 = xr[lane], v1 = xr[lane + 64];
  float s = v0 + v1, s2 = v0 * v0 + v1 * v1;
  #pragma unroll
  for (int off = 32; off > 0; off >>= 1) {
    s  += __shfl_xor(s,  off);
    s2 += __shfl_xor(s2, off);
  }
  float mu = s * (1.f / 128.f);
  float var = s2 * (1.f / 128.f) - mu * mu;
  float rs = rsqrtf(var + 1e-5f);
  __hip_bfloat16* o = xw + (size_t)wid * 128;
  o[lane]      = __float2bfloat16((v0 - mu) * rs * g[lane]      + bta[lane]);
  o[lane + 64] = __float2bfloat16((v1 - mu) * rs * g[lane + 64] + bta[lane + 64]);
}

// ---------------------------------------------------------------------------
// bf16 MFMA GEMM: C = A @ Wt^T + bias.
// EPI 0: plain store (OUTBF selects bf16/f32).
// EPI 3: proj+scatter fused epilogue: row -> (i0+li, n); n<5 -> pbuf,
//        else out[spatial] = xres[spatial] + t. Cout=out(f32), Rres=x.
// ---------------------------------------------------------------------------
template<int EPI, int OUTBF>
__global__ __launch_bounds__(256) void gemm_mfma(
    const __hip_bfloat16* __restrict__ A, const __hip_bfloat16* __restrict__ Wt,
    const float* __restrict__ bias, void* __restrict__ Cout,
    const float* __restrict__ Rres, float* __restrict__ pbuf, int i0,
    int Mstore, int N, int K)
{
  __shared__ short As[8192];
  __shared__ short Ws[8192];
  const int tid = threadIdx.x;
  const int wv = tid >> 6, lane = tid & 63;
  const int m0 = blockIdx.y * 128, n0 = blockIdx.x * 128;
  const int wr = wv >> 1, wc = wv & 1;
  f32x4 acc[4][4] = {};
  const int srow = wv * 8 + (lane >> 3);
  const int schunk = lane & 7;

  for (int k0 = 0; k0 < K; k0 += 64) {
    #pragma unroll
    for (int i = 0; i < 4; ++i) {
      int row = i * 32 + srow;
      int kk = k0 + ((schunk ^ (row & 7)) << 3);
      const __hip_bfloat16* ga = A  + (size_t)(m0 + row) * K + kk;
      const __hip_bfloat16* gw = Wt + (size_t)(n0 + row) * K + kk;
      __builtin_amdgcn_global_load_lds(
          (const __attribute__((address_space(1))) void*)ga,
          (__attribute__((address_space(3))) void*)(As + i * 2048 + wv * 512),
          16, 0, 0);
      __builtin_amdgcn_global_load_lds(
          (const __attribute__((address_space(1))) void*)gw,
          (__attribute__((address_space(3))) void*)(Ws + i * 2048 + wv * 512),
          16, 0, 0);
    }
    __syncthreads();
    #pragma unroll
    for (int s = 0; s < 2; ++s) {
      bf16x8 af[4], bfr[4];
      #pragma unroll
      for (int mi = 0; mi < 4; ++mi) {
        int r = wr * 64 + mi * 16 + (lane & 15);
        int ch = ((s << 2) + (lane >> 4)) ^ (r & 7);
        af[mi] = *(const bf16x8*)(As + r * 64 + ch * 8);
      }
      #pragma unroll
      for (int ni = 0; ni < 4; ++ni) {
        int r = wc * 64 + ni * 16 + (lane & 15);
        int ch = ((s << 2) + (lane >> 4)) ^ (r & 7);
        bfr[ni] = *(const bf16x8*)(Ws + r * 64 + ch * 8);
      }
      #pragma unroll
      for (int mi = 0; mi < 4; ++mi)
        #pragma unroll
        for (int ni = 0; ni < 4; ++ni)
          acc[mi][ni] = __builtin_amdgcn_mfma_f32_16x16x32_bf16(
              af[mi], bfr[ni], acc[mi][ni], 0, 0, 0);
    }
    __syncthreads();
  }
  const int cl = lane & 15, rh = lane >> 4;
  #pragma unroll
  for (int mi = 0; mi < 4; ++mi) {
    #pragma unroll
    for (int r = 0; r < 4; ++r) {
      int grow = m0 + wr * 64 + mi * 16 + rh * 4 + r;
      if (grow < Mstore) {
        if (EPI == 3) {
          int li = grow / 54, n = grow - li * 54;
          int gi = i0 + li;
          if (n < 5) {
            #pragma unroll
            for (int ni = 0; ni < 4; ++ni) {
              int gcol = n0 + wc * 64 + ni * 16 + cl;
              pbuf[((size_t)gi * 5 + n) * 128 + gcol] = acc[mi][ni][r] + bias[gcol];
            }
          } else {
            int b = gi >> 6, w = gi & 63, tt = n - 5;
            int rr = (w >> 3) * 7 + tt / 7 + 3; if (rr >= 56) rr -= 56;
            int cc = (w & 7) * 7 + tt % 7 + 3;  if (cc >= 56) cc -= 56;
            size_t ob = ((size_t)b * 3141 + 5 + rr * 56 + cc) * 128;
            #pragma unroll
            for (int ni = 0; ni < 4; ++ni) {
              int gcol = n0 + wc * 64 + ni * 16 + cl;
              ((float*)Cout)[ob + gcol] = Rres[ob + gcol] + acc[mi][ni][r] + bias[gcol];
            }
          }
        } else {
          #pragma unroll
          for (int ni = 0; ni < 4; ++ni) {
            int gcol = n0 + wc * 64 + ni * 16 + cl;
            float t = acc[mi][ni][r] + bias[gcol];
            if (OUTBF)
              ((__hip_bfloat16*)Cout)[(size_t)grow * N + gcol] = __float2bfloat16(t);
            else
              ((float*)Cout)[(size_t)grow * N + gcol] = t;
          }
        }
      }
    }
  }
}

// ---------------------------------------------------------------------------
// MFMA attention (unchanged from round 3): block = window-row, wave = head.
// ---------------------------------------------------------------------------
__global__ __launch_bounds__(256) void attn_mfma(
    const __hip_bfloat16* __restrict__ qkv,
    const __hip_bfloat16* __restrict__ bias_tab,
    __hip_bfloat16* __restrict__ attn_out, int i0)
{
  __shared__ short lds[24576];
  const int tid = threadIdx.x;
  const int h = tid >> 6, lane = tid & 63;
  const int li = blockIdx.x;
  const int w = (i0 + li) & 63;
  const int c = lane & 15, g = lane >> 4;
  short* Lh = lds + h * 6144;
  const unsigned short* qk = (const unsigned short*)qkv;

  #pragma unroll
  for (int m = 0; m < 3; ++m) {
    #pragma unroll
    for (int t = 0; t < 4; ++t) {
      int tok = t * 16 + (lane >> 2);
      int swz = (m == 2) ? ((tok >> 3) & 3) : ((tok >> 1) & 3);
      int ch = (lane & 3) ^ swz;
      const unsigned short* ga = qk + (size_t)(li * 54 + tok) * 384 + m * 128 + h * 32 + ch * 8;
      __builtin_amdgcn_global_load_lds(
          (const __attribute__((address_space(1))) void*)ga,
          (__attribute__((address_space(3))) void*)(Lh + m * 2048 + t * 512),
          16, 0, 0);
    }
  }

  const unsigned short* bt = (const unsigned short*)bias_tab + ((size_t)(w * 4 + h) << 12);
  u16x4 bb[4][4];
  #pragma unroll
  for (int ni = 0; ni < 4; ++ni)
    #pragma unroll
    for (int mi = 0; mi < 4; ++mi)
      bb[ni][mi] = *(const u16x4*)(bt + (ni * 16 + c) * 64 + mi * 16 + g * 4);

  asm volatile("s_waitcnt vmcnt(0)" ::: "memory");
  __builtin_amdgcn_sched_barrier(0);

  bf16x8 af[4], bq[4];
  #pragma unroll
  for (int mi = 0; mi < 4; ++mi) {
    int tok = mi * 16 + c;
    af[mi] = *(const bf16x8*)(Lh + 2048 + tok * 32 + ((g ^ ((tok >> 1) & 3)) << 3));
  }
  #pragma unroll
  for (int ni = 0; ni < 4; ++ni) {
    int q = ni * 16 + c;
    bq[ni] = *(const bf16x8*)(Lh + q * 32 + ((g ^ ((q >> 1) & 3)) << 3));
  }
  f32x4 acc[4][4] = {};
  #pragma unroll
  for (int mi = 0; mi < 4; ++mi)
    #pragma unroll
    for (int ni = 0; ni < 4; ++ni)
      acc[mi][ni] = __builtin_amdgcn_mfma_f32_16x16x32_bf16(af[mi], bq[ni], acc[mi][ni], 0, 0, 0);

  const float SC = 0.17677669529663689f * 1.44269504088896f;
  #pragma unroll
  for (int ni = 0; ni < 4; ++ni)
    #pragma unroll
    for (int mi = 0; mi < 4; ++mi)
      #pragma unroll
      for (int r = 0; r < 4; ++r)
        acc[mi][ni][r] = acc[mi][ni][r] * SC + bf2f(bb[ni][mi][r]);

  #pragma unroll
  for (int ni = 0; ni < 4; ++ni) {
    float m2 = -3.0e38f;
    #pragma unroll
    for (int mi = 0; mi < 4; ++mi)
      #pragma unroll
      for (int r = 0; r < 4; ++r)
        m2 = fmaxf(m2, acc[mi][ni][r]);
    m2 = fmaxf(m2, __shfl_xor(m2, 16, 64));
    m2 = fmaxf(m2, __shfl_xor(m2, 32, 64));
    float sm = 0.f;
    #pragma unroll
    for (int mi = 0; mi < 4; ++mi)
      #pragma unroll
      for (int r = 0; r < 4; ++r) {
        float p = exp2f(acc[mi][ni][r] - m2);
        acc[mi][ni][r] = p;
        sm += p;
      }
    sm += __shfl_xor(sm, 16, 64);
    sm += __shfl_xor(sm, 32, 64);
    float inv = 1.0f / sm;
    int q = ni * 16 + c;
    #pragma unroll
    for (int mi = 0; mi < 4; ++mi) {
      u16x4 pw;
      #pragma unroll
      for (int r = 0; r < 4; ++r) pw[r] = f2b(acc[mi][ni][r] * inv);
      int chp = (mi * 2 + (g >> 1)) ^ (q & 7);
      *(u16x4*)(Lh + q * 64 + chp * 8 + (g & 1) * 4) = pw;
    }
  }

  f32x4 acc2[4][2] = {};
  #pragma unroll
  for (int ks = 0; ks < 2; ++ks) {
    bf16x8 pa[4];
    #pragma unroll
    for (int qi = 0; qi < 4; ++qi) {
      int q = qi * 16 + c;
      int chk = (ks * 4 + g) ^ (q & 7);
      pa[qi] = *(const bf16x8*)(Lh + q * 64 + chk * 8);
    }
    bf16x8 vb[2];
    #pragma unroll
    for (int di = 0; di < 2; ++di) {
      #pragma unroll
      for (int j = 0; j < 8; ++j) {
        int k = ks * 32 + g * 8 + j;
        int chv = ((di * 2 + (c >> 3)) ^ g);
        vb[di][j] = Lh[4096 + k * 32 + chv * 8 + (c & 7)];
      }
    }
    #pragma unroll
    for (int qi = 0; qi < 4; ++qi)
      #pragma unroll
      for (int di = 0; di < 2; ++di)
        acc2[qi][di] = __builtin_amdgcn_mfma_f32_16x16x32_bf16(pa[qi], vb[di], acc2[qi][di], 0, 0, 0);
  }

  #pragma unroll
  for (int qi = 0; qi < 4; ++qi) {
    #pragma unroll
    for (int r = 0; r < 4; ++r) {
      int q = qi * 16 + g * 4 + r;
      if (q < 54) {
        __hip_bfloat16* orow = attn_out + (size_t)(li * 54 + q) * 128 + h * 32;
        #pragma unroll
        for (int di = 0; di < 2; ++di)
          orow[di * 16 + c] = __float2bfloat16(acc2[qi][di][r]);
      }
    }
  }
}

// ---------------------------------------------------------------------------
// Prompt mean over windows + residual
// ---------------------------------------------------------------------------
__global__ __launch_bounds__(128) void prompt_reduce(const float* __restrict__ x,
    const float* __restrict__ pbuf, float* __restrict__ out)
{
  int bp = blockIdx.x;
  int b = bp / 5, p = bp % 5;
  int c = threadIdx.x;
  float s = 0.f;
  for (int w = 0; w < 64; ++w)
    s += pbuf[((size_t)(w * 64 + b) * 5 + p) * 128 + c];
  size_t oidx = ((size_t)b * 3141 + p) * 128 + c;
  out[oidx] = x[oidx] + s * (1.f / 64.f);
}

// ---------------------------------------------------------------------------
// Fused MLP: out = x + fc2(gelu(fc1(LN2(x)))).  64 rows/block, 4 waves.
// Strip-mined over fc1's 512 cols (4 strips of 128); h kept in LDS; fc2
// accumulates in registers across strips. In-place (outp == xin) is safe.
// LDS 64KB: xn[64][128] @0, h[64][128] @8192, wb[128][128] @16384 (shorts).
// Wave tile: 64 rows x 32 cols (frags 4x2).
// ---------------------------------------------------------------------------
__global__ __launch_bounds__(256, 2) void mlp_fused(
    const float* __restrict__ xin,
    const float* __restrict__ gamma, const float* __restrict__ beta,
    const __hip_bfloat16* __restrict__ w1t, const float* __restrict__ b1,
    const __hip_bfloat16* __restrict__ w2t, const float* __restrict__ b2,
    float* __restrict__ outp)
{
  __shared__ short lds[32768];
  short* xn = lds;
  short* hb = lds + 8192;
  short* wb = lds + 16384;
  const int tid = threadIdx.x;
  const int wv = tid >> 6, lane = tid & 63;
  const int c = lane & 15, g = lane >> 4;
  const int r0 = blockIdx.x * 64;

  // ---- LN2: wave wv handles rows wv*16..+15
  for (int rr = 0; rr < 16; ++rr) {
    int row = wv * 16 + rr;
    const float* xr = xin + (size_t)(r0 + row) * 128;
    float v0 = xr[lane], v1 = xr[lane + 64];
    float s = v0 + v1, s2 = v0 * v0 + v1 * v1;
    #pragma unroll
    for (int off = 32; off > 0; off >>= 1) {
      s  += __shfl_xor(s,  off);
      s2 += __shfl_xor(s2, off);
    }
    float mu = s * (1.f / 128.f);
    float var = s2 * (1.f / 128.f) - mu * mu;
    float rs = rsqrtf(var + 1e-5f);
    float y0 = (v0 - mu) * rs * gamma[lane]      + beta[lane];
    float y1 = (v1 - mu) * rs * gamma[lane + 64] + beta[lane + 64];
    int na = lane, nbb = lane + 64;
    xn[row * 128 + ((((na  >> 3)) ^ (row & 7)) << 3) + (na  & 7)] = (short)f2b(y0);
    xn[row * 128 + ((((nbb >> 3)) ^ (row & 7)) << 3) + (nbb & 7)] = (short)f2b(y1);
  }
  __syncthreads();

  f32x4 acc2[4][2] = {};
  for (int s = 0; s < 4; ++s) {
    // ---- stage w1 strip s -> wb (128 rows x 128 k)
    #pragma unroll
    for (int p = 0; p < 8; ++p) {
      int wrow = p * 16 + wv * 4 + (lane >> 4);
      int ch = (lane & 15) ^ (wrow & 7);
      const __hip_bfloat16* ga = w1t + (size_t)(s * 128 + wrow) * 128 + ch * 8;
      __builtin_amdgcn_global_load_lds(
          (const __attribute__((address_space(1))) void*)ga,
          (__attribute__((address_space(3))) void*)(wb + p * 2048 + wv * 512),
          16, 0, 0);
    }
    __syncthreads();
    // ---- fc1: acc1 = xn @ w1s^T
    f32x4 acc1[4][2] = {};
    #pragma unroll
    for (int ks = 0; ks < 4; ++ks) {
      bf16x8 af[4], bf[2];
      #pragma unroll
      for (int mi = 0; mi < 4; ++mi) {
        int row = mi * 16 + c;
        af[mi] = *(const bf16x8*)(xn + row * 128 + (((ks * 4 + g) ^ (row & 7)) << 3));
      }
      #pragma unroll
      for (int ni = 0; ni < 2; ++ni) {
        int wrow = wv * 32 + ni * 16 + c;
        bf[ni] = *(const bf16x8*)(wb + wrow * 128 + (((ks * 4 + g) ^ (wrow & 7)) << 3));
      }
      #pragma unroll
      for (int mi = 0; mi < 4; ++mi)
        #pragma unroll
        for (int ni = 0; ni < 2; ++ni)
          acc1[mi][ni] = __builtin_amdgcn_mfma_f32_16x16x32_bf16(
              af[mi], bf[ni], acc1[mi][ni], 0, 0, 0);
    }
    // ---- GELU + write h (bf16, swizzled)
    #pragma unroll
    for (int ni = 0; ni < 2; ++ni) {
      int col = wv * 32 + ni * 16 + c;
      float bv = b1[s * 128 + col];
      #pragma unroll
      for (int mi = 0; mi < 4; ++mi) {
        #pragma unroll
        for (int r = 0; r < 4; ++r) {
          int row = mi * 16 + g * 4 + r;
          float t = acc1[mi][ni][r] + bv;
          t = 0.5f * t * (1.f + erff(t * 0.70710678118654752f));
          hb[row * 128 + (((col >> 3) ^ (row & 7)) << 3) + (col & 7)] = (short)f2b(t);
        }
      }
    }
    __syncthreads();
    // ---- stage w2 strip -> wb (128 out-cols x 128 k)
    #pragma unroll
    for (int p = 0; p < 8; ++p) {
      int wrow = p * 16 + wv * 4 + (lane >> 4);
      int ch = (lane & 15) ^ (wrow & 7);
      const __hip_bfloat16* ga = w2t + (size_t)wrow * 512 + s * 128 + ch * 8;
      __builtin_amdgcn_global_load_lds(
          (const __attribute__((address_space(1))) void*)ga,
          (__attribute__((address_space(3))) void*)(wb + p * 2048 + wv * 512),
          16, 0, 0);
    }
    __syncthreads();
    // ---- fc2: acc2 += h @ w2s^T
    #pragma unroll
    for (int ks = 0; ks < 4; ++ks) {
      bf16x8 af[4], bf[2];
      #pragma unroll
      for (int mi = 0; mi < 4; ++mi) {
        int row = mi * 16 + c;
        af[mi] = *(const bf16x8*)(hb + row * 128 + (((ks * 4 + g) ^ (row & 7)) << 3));
      }
      #pragma unroll
      for (int ni = 0; ni < 2; ++ni) {
        int wrow = wv * 32 + ni * 16 + c;
        bf[ni] = *(const bf16x8*)(wb + wrow * 128 + (((ks * 4 + g) ^ (wrow & 7)) << 3));
      }
      #pragma unroll
      for (int mi = 0; mi < 4; ++mi)
        #pragma unroll
        for (int ni = 0; ni < 2; ++ni)
          acc2[mi][ni] = __builtin_amdgcn_mfma_f32_16x16x32_bf16(
              af[mi], bf[ni], acc2[mi][ni], 0, 0, 0);
    }
    __syncthreads();
  }

  // ---- epilogue: out = acc2 + b2 + x
  #pragma unroll
  for (int mi = 0; mi < 4; ++mi) {
    #pragma unroll
    for (int r = 0; r < 4; ++r) {
      int row = r0 + mi * 16 + g * 4 + r;
      #pragma unroll
      for (int ni = 0; ni < 2; ++ni) {
        int col = wv * 32 + ni * 16 + c;
        size_t o = (size_t)row * 128 + col;
        outp[o] = acc2[mi][ni][r] + b2[col] + xin[o];
      }
    }
  }
}

// ---------------------------------------------------------------------------
// Launch
// ---------------------------------------------------------------------------
extern "C" void kernel_launch(void* const* d_in, const int* in_sizes, int n_in,
                              void* d_out, int out_size, void* d_ws, size_t ws_size,
                              hipStream_t stream) {
  const float* x      = (const float*)d_in[0];
  const float* n1g    = (const float*)d_in[1];
  const float* n1b    = (const float*)d_in[2];
  const float* qkv_w  = (const float*)d_in[3];
  const float* qkv_b  = (const float*)d_in[4];
  const float* proj_w = (const float*)d_in[5];
  const float* proj_b = (const float*)d_in[6];
  const float* rpb    = (const float*)d_in[7];
  const float* n2g    = (const float*)d_in[8];
  const float* n2b    = (const float*)d_in[9];
  const float* fc1w   = (const float*)d_in[10];
  const float* fc1b   = (const float*)d_in[11];
  const float* fc2w   = (const float*)d_in[12];
  const float* fc2b   = (const float*)d_in[13];
  float* out = (float*)d_out;
  char* ws = (char*)d_ws;

  // ws layout (bytes):
  //   [0, 393216)          bf16 weights (transposed)
  //   [393216, 2490368)    bias table (2 MB)
  //   [2490368, 12976128)  pbuf
  //   [12976128, ...)      phase-1 chunk buffers
  __hip_bfloat16* wbuf = (__hip_bfloat16*)ws;
  __hip_bfloat16* w_qkv = wbuf;
  __hip_bfloat16* w_prj = wbuf + 49152;
  __hip_bfloat16* w_fc1 = wbuf + 65536;
  __hip_bfloat16* w_fc2 = wbuf + 131072;
  __hip_bfloat16* bias_tab = (__hip_bfloat16*)(ws + 393216);
  float* pbuf = (float*)(ws + 2490368);
  const size_t CHUNK_BASE = 12976128ULL;

  hipLaunchKernelGGL(convert_wt, dim3(192), dim3(256), 0, stream, qkv_w, w_qkv, 128, 384);
  hipLaunchKernelGGL(convert_wt, dim3(64),  dim3(256), 0, stream, proj_w, w_prj, 128, 128);
  hipLaunchKernelGGL(convert_wt, dim3(256), dim3(256), 0, stream, fc1w,  w_fc1, 128, 512);
  hipLaunchKernelGGL(convert_wt, dim3(256), dim3(256), 0, stream, fc2w,  w_fc2, 512, 128);
  hipLaunchKernelGGL(bias_gen, dim3(256), dim3(256), 0, stream, rpb, bias_tab);

  // ---- Phase 1: LN1 -> QKV -> attn(MFMA) -> proj(+scatter fused)
  int cw = 2048;
  while (cw > 64 && CHUNK_BASE + (size_t)cw * 54 * 1024 + 8192 > ws_size) cw >>= 1;
  {
    size_t R = (size_t)cw * 54;
    __hip_bfloat16* xw_c  = (__hip_bfloat16*)(ws + CHUNK_BASE);
    __hip_bfloat16* qkv_c = (__hip_bfloat16*)(ws + CHUNK_BASE + R * 256);
    for (int i0 = 0; i0 < 4096; i0 += cw) {
      int nr = cw * 54;
      hipLaunchKernelGGL(ln1_gather, dim3((nr + 3) / 4), dim3(256), 0, stream,
                         x, n1g, n1b, xw_c, i0, nr);
      hipLaunchKernelGGL((gemm_mfma<0, 1>), dim3(3, nr / 128), dim3(256), 0, stream,
                         xw_c, w_qkv, qkv_b, qkv_c, (const float*)nullptr,
                         (float*)nullptr, 0, nr, 384, 128);
      hipLaunchKernelGGL(attn_mfma, dim3(cw), dim3(256), 0, stream,
                         qkv_c, bias_tab, xw_c, i0);
      hipLaunchKernelGGL((gemm_mfma<3, 0>), dim3(1, nr / 128), dim3(256), 0, stream,
                         xw_c, w_prj, proj_b, (void*)out, x, pbuf, i0, nr, 128, 128);
    }
    hipLaunchKernelGGL(prompt_reduce, dim3(320), dim3(128), 0, stream, x, pbuf, out);
  }

  // ---- Phase 2: fused MLP (in-place on out), 201024 = 3141*64 rows
  hipLaunchKernelGGL(mlp_fused, dim3(3141), dim3(256), 0, stream,
                     out, n2g, n2b, w_fc1, fc1b, w_fc2, fc2b, out);
  (void)in_sizes; (void)n_in; (void)out_size; (void)ws_size;
}

// Round 6
// 477.548 us; speedup vs baseline: 3.8124x; 1.0144x over previous
//
#include <hip/hip_runtime.h>
#include <hip/hip_bf16.h>
#include <math.h>

// H=W=56, C=128, WS=7, SS=3, NH=4, P=5, HD=32, NW=64, NTOK=49, N=54, B=64
// x rows: 3141 = 5 + 56*56; window-rows: 4096 = B*NW; tokens/window: 54

typedef __attribute__((ext_vector_type(8))) short bf16x8;
typedef __attribute__((ext_vector_type(4))) float f32x4;
typedef __attribute__((ext_vector_type(4))) unsigned short u16x4;

__device__ __forceinline__ float bf2f(unsigned short u) {
  union { unsigned int i; float f; } v; v.i = ((unsigned)u) << 16; return v.f;
}
__device__ __forceinline__ unsigned short f2b(float f) {
  __hip_bfloat16 b = __float2bfloat16(f);
  return *reinterpret_cast<unsigned short*>(&b);
}
// 4-bit nibble swap: maps rows {r,4+r,8+r,12+r} to 4 distinct low-2-bits
__device__ __forceinline__ int swapnib(int x) { return ((x >> 2) & 3) | ((x & 3) << 2); }

// ---------------------------------------------------------------------------
// Weight convert: wt[n][k] = bf16(w[k][n])
// ---------------------------------------------------------------------------
__global__ __launch_bounds__(256) void convert_wt(const float* __restrict__ w,
    __hip_bfloat16* __restrict__ wt, int K, int N)
{
  int idx = blockIdx.x * 256 + threadIdx.x;
  if (idx >= N * K) return;
  int n = idx / K, k = idx % K;
  wt[idx] = __float2bfloat16(w[(size_t)k * N + n]);
}

// ---------------------------------------------------------------------------
// Bias table gen (once): bias2[w][h][q][k] bf16, exp2-domain; k>=54 -> -inf
// ---------------------------------------------------------------------------
__global__ __launch_bounds__(256) void bias_gen(const float* __restrict__ rpb,
    __hip_bfloat16* __restrict__ tab)
{
  int w = blockIdx.x >> 2, h = blockIdx.x & 3;
  int wh = w >> 3, ww = w & 7;
  #pragma unroll
  for (int e = 0; e < 16; ++e) {
    int fi = e * 256 + threadIdx.x;
    int q = fi >> 6, k = fi & 63;
    float v;
    if (k >= 54) {
      v = -INFINITY;
    } else {
      v = 0.f;
      if (q >= 5 && q < 54 && k >= 5) {
        int tq = q - 5, tk = k - 5;
        int aq = tq / 7, bq_ = tq % 7, ak = tk / 7, bk = tk % 7;
        int dh = aq - ak + 6, dw = bq_ - bk + 6;
        v = rpb[(dh * 13 + dw) * 4 + h];
        int rq = wh * 7 + aq, cq = ww * 7 + bq_;
        int rk = wh * 7 + ak, ck = ww * 7 + bk;
        int zq = (rq < 49 ? 0 : (rq < 53 ? 1 : 2)) * 3 + (cq < 49 ? 0 : (cq < 53 ? 1 : 2));
        int zk = (rk < 49 ? 0 : (rk < 53 ? 1 : 2)) * 3 + (ck < 49 ? 0 : (ck < 53 ? 1 : 2));
        if (zq != zk) v += -100.f;
      }
      v *= 1.44269504088896f;
    }
    tab[((size_t)blockIdx.x << 12) + fi] = __float2bfloat16(v);
  }
}

// ---------------------------------------------------------------------------
// LN1 + window gather -> xw_c bf16
// ---------------------------------------------------------------------------
__global__ __launch_bounds__(256) void ln1_gather(const float* __restrict__ x,
    const float* __restrict__ g, const float* __restrict__ bta,
    __hip_bfloat16* __restrict__ xw, int i0, int nrows)
{
  int wid = blockIdx.x * 4 + (threadIdx.x >> 6);
  if (wid >= nrows) return;
  int lane = threadIdx.x & 63;
  int i = i0 + wid / 54, n = wid % 54;
  int src;
  if (n < 5) {
    src = (i & 63) * 3141 + n;
  } else {
    int b = i >> 6, w = i & 63;
    int t = n - 5;
    int hp = (w >> 3) * 7 + t / 7 + 3; if (hp >= 56) hp -= 56;
    int wp = (w & 7) * 7 + t % 7 + 3;  if (wp >= 56) wp -= 56;
    src = b * 3141 + 5 + hp * 56 + wp;
  }
  const float* xr = x + (size_t)src * 128;
  float v0 = xr[lane], v1 = xr[lane + 64];
  float s = v0 + v1, s2 = v0 * v0 + v1 * v1;
  #pragma unroll
  for (int off = 32; off > 0; off >>= 1) {
    s  += __shfl_xor(s,  off);
    s2 += __shfl_xor(s2, off);
  }
  float mu = s * (1.f / 128.f);
  float var = s2 * (1.f / 128.f) - mu * mu;
  float rs = rsqrtf(var + 1e-5f);
  __hip_bfloat16* o = xw + (size_t)wid * 128;
  o[lane]      = __float2bfloat16((v0 - mu) * rs * g[lane]      + bta[lane]);
  o[lane + 64] = __float2bfloat16((v1 - mu) * rs * g[lane + 64] + bta[lane + 64]);
}

// ---------------------------------------------------------------------------
// bf16 MFMA GEMM: C = A @ Wt^T + bias.
// EPI 0: plain store (OUTBF selects bf16/f32).
// EPI 3: proj+scatter fused epilogue.
// ---------------------------------------------------------------------------
template<int EPI, int OUTBF>
__global__ __launch_bounds__(256) void gemm_mfma(
    const __hip_bfloat16* __restrict__ A, const __hip_bfloat16* __restrict__ Wt,
    const float* __restrict__ bias, void* __restrict__ Cout,
    const float* __restrict__ Rres, float* __restrict__ pbuf, int i0,
    int Mstore, int N, int K)
{
  __shared__ short As[8192];
  __shared__ short Ws[8192];
  const int tid = threadIdx.x;
  const int wv = tid >> 6, lane = tid & 63;
  const int m0 = blockIdx.y * 128, n0 = blockIdx.x * 128;
  const int wr = wv >> 1, wc = wv & 1;
  f32x4 acc[4][4] = {};
  const int srow = wv * 8 + (lane >> 3);
  const int schunk = lane & 7;

  for (int k0 = 0; k0 < K; k0 += 64) {
    #pragma unroll
    for (int i = 0; i < 4; ++i) {
      int row = i * 32 + srow;
      int kk = k0 + ((schunk ^ (row & 7)) << 3);
      const __hip_bfloat16* ga = A  + (size_t)(m0 + row) * K + kk;
      const __hip_bfloat16* gw = Wt + (size_t)(n0 + row) * K + kk;
      __builtin_amdgcn_global_load_lds(
          (const __attribute__((address_space(1))) void*)ga,
          (__attribute__((address_space(3))) void*)(As + i * 2048 + wv * 512),
          16, 0, 0);
      __builtin_amdgcn_global_load_lds(
          (const __attribute__((address_space(1))) void*)gw,
          (__attribute__((address_space(3))) void*)(Ws + i * 2048 + wv * 512),
          16, 0, 0);
    }
    __syncthreads();
    #pragma unroll
    for (int s = 0; s < 2; ++s) {
      bf16x8 af[4], bfr[4];
      #pragma unroll
      for (int mi = 0; mi < 4; ++mi) {
        int r = wr * 64 + mi * 16 + (lane & 15);
        int ch = ((s << 2) + (lane >> 4)) ^ (r & 7);
        af[mi] = *(const bf16x8*)(As + r * 64 + ch * 8);
      }
      #pragma unroll
      for (int ni = 0; ni < 4; ++ni) {
        int r = wc * 64 + ni * 16 + (lane & 15);
        int ch = ((s << 2) + (lane >> 4)) ^ (r & 7);
        bfr[ni] = *(const bf16x8*)(Ws + r * 64 + ch * 8);
      }
      #pragma unroll
      for (int mi = 0; mi < 4; ++mi)
        #pragma unroll
        for (int ni = 0; ni < 4; ++ni)
          acc[mi][ni] = __builtin_amdgcn_mfma_f32_16x16x32_bf16(
              af[mi], bfr[ni], acc[mi][ni], 0, 0, 0);
    }
    __syncthreads();
  }
  const int cl = lane & 15, rh = lane >> 4;
  #pragma unroll
  for (int mi = 0; mi < 4; ++mi) {
    #pragma unroll
    for (int r = 0; r < 4; ++r) {
      int grow = m0 + wr * 64 + mi * 16 + rh * 4 + r;
      if (grow < Mstore) {
        if (EPI == 3) {
          int li = grow / 54, n = grow - li * 54;
          int gi = i0 + li;
          if (n < 5) {
            #pragma unroll
            for (int ni = 0; ni < 4; ++ni) {
              int gcol = n0 + wc * 64 + ni * 16 + cl;
              pbuf[((size_t)gi * 5 + n) * 128 + gcol] = acc[mi][ni][r] + bias[gcol];
            }
          } else {
            int b = gi >> 6, w = gi & 63, tt = n - 5;
            int rr = (w >> 3) * 7 + tt / 7 + 3; if (rr >= 56) rr -= 56;
            int cc = (w & 7) * 7 + tt % 7 + 3;  if (cc >= 56) cc -= 56;
            size_t ob = ((size_t)b * 3141 + 5 + rr * 56 + cc) * 128;
            #pragma unroll
            for (int ni = 0; ni < 4; ++ni) {
              int gcol = n0 + wc * 64 + ni * 16 + cl;
              ((float*)Cout)[ob + gcol] = Rres[ob + gcol] + acc[mi][ni][r] + bias[gcol];
            }
          }
        } else {
          #pragma unroll
          for (int ni = 0; ni < 4; ++ni) {
            int gcol = n0 + wc * 64 + ni * 16 + cl;
            float t = acc[mi][ni][r] + bias[gcol];
            if (OUTBF)
              ((__hip_bfloat16*)Cout)[(size_t)grow * N + gcol] = __float2bfloat16(t);
            else
              ((float*)Cout)[(size_t)grow * N + gcol] = t;
          }
        }
      }
    }
  }
}

// ---------------------------------------------------------------------------
// MFMA attention: block = window-row, wave = head. Barrier-free.
// ---------------------------------------------------------------------------
__global__ __launch_bounds__(256) void attn_mfma(
    const __hip_bfloat16* __restrict__ qkv,
    const __hip_bfloat16* __restrict__ bias_tab,
    __hip_bfloat16* __restrict__ attn_out, int i0)
{
  __shared__ short lds[24576];
  const int tid = threadIdx.x;
  const int h = tid >> 6, lane = tid & 63;
  const int li = blockIdx.x;
  const int w = (i0 + li) & 63;
  const int c = lane & 15, g = lane >> 4;
  short* Lh = lds + h * 6144;
  const unsigned short* qk = (const unsigned short*)qkv;

  #pragma unroll
  for (int m = 0; m < 3; ++m) {
    #pragma unroll
    for (int t = 0; t < 4; ++t) {
      int tok = t * 16 + (lane >> 2);
      int swz = (m == 2) ? ((tok >> 3) & 3) : ((tok >> 1) & 3);
      int ch = (lane & 3) ^ swz;
      const unsigned short* ga = qk + (size_t)(li * 54 + tok) * 384 + m * 128 + h * 32 + ch * 8;
      __builtin_amdgcn_global_load_lds(
          (const __attribute__((address_space(1))) void*)ga,
          (__attribute__((address_space(3))) void*)(Lh + m * 2048 + t * 512),
          16, 0, 0);
    }
  }

  const unsigned short* bt = (const unsigned short*)bias_tab + ((size_t)(w * 4 + h) << 12);
  u16x4 bb[4][4];
  #pragma unroll
  for (int ni = 0; ni < 4; ++ni)
    #pragma unroll
    for (int mi = 0; mi < 4; ++mi)
      bb[ni][mi] = *(const u16x4*)(bt + (ni * 16 + c) * 64 + mi * 16 + g * 4);

  asm volatile("s_waitcnt vmcnt(0)" ::: "memory");
  __builtin_amdgcn_sched_barrier(0);

  bf16x8 af[4], bq[4];
  #pragma unroll
  for (int mi = 0; mi < 4; ++mi) {
    int tok = mi * 16 + c;
    af[mi] = *(const bf16x8*)(Lh + 2048 + tok * 32 + ((g ^ ((tok >> 1) & 3)) << 3));
  }
  #pragma unroll
  for (int ni = 0; ni < 4; ++ni) {
    int q = ni * 16 + c;
    bq[ni] = *(const bf16x8*)(Lh + q * 32 + ((g ^ ((q >> 1) & 3)) << 3));
  }
  f32x4 acc[4][4] = {};
  #pragma unroll
  for (int mi = 0; mi < 4; ++mi)
    #pragma unroll
    for (int ni = 0; ni < 4; ++ni)
      acc[mi][ni] = __builtin_amdgcn_mfma_f32_16x16x32_bf16(af[mi], bq[ni], acc[mi][ni], 0, 0, 0);

  const float SC = 0.17677669529663689f * 1.44269504088896f;
  #pragma unroll
  for (int ni = 0; ni < 4; ++ni)
    #pragma unroll
    for (int mi = 0; mi < 4; ++mi)
      #pragma unroll
      for (int r = 0; r < 4; ++r)
        acc[mi][ni][r] = acc[mi][ni][r] * SC + bf2f(bb[ni][mi][r]);

  #pragma unroll
  for (int ni = 0; ni < 4; ++ni) {
    float m2 = -3.0e38f;
    #pragma unroll
    for (int mi = 0; mi < 4; ++mi)
      #pragma unroll
      for (int r = 0; r < 4; ++r)
        m2 = fmaxf(m2, acc[mi][ni][r]);
    m2 = fmaxf(m2, __shfl_xor(m2, 16, 64));
    m2 = fmaxf(m2, __shfl_xor(m2, 32, 64));
    float sm = 0.f;
    #pragma unroll
    for (int mi = 0; mi < 4; ++mi)
      #pragma unroll
      for (int r = 0; r < 4; ++r) {
        float p = exp2f(acc[mi][ni][r] - m2);
        acc[mi][ni][r] = p;
        sm += p;
      }
    sm += __shfl_xor(sm, 16, 64);
    sm += __shfl_xor(sm, 32, 64);
    float inv = 1.0f / sm;
    int q = ni * 16 + c;
    #pragma unroll
    for (int mi = 0; mi < 4; ++mi) {
      u16x4 pw;
      #pragma unroll
      for (int r = 0; r < 4; ++r) pw[r] = f2b(acc[mi][ni][r] * inv);
      int chp = (mi * 2 + (g >> 1)) ^ (q & 7);
      *(u16x4*)(Lh + q * 64 + chp * 8 + (g & 1) * 4) = pw;
    }
  }

  f32x4 acc2[4][2] = {};
  #pragma unroll
  for (int ks = 0; ks < 2; ++ks) {
    bf16x8 pa[4];
    #pragma unroll
    for (int qi = 0; qi < 4; ++qi) {
      int q = qi * 16 + c;
      int chk = (ks * 4 + g) ^ (q & 7);
      pa[qi] = *(const bf16x8*)(Lh + q * 64 + chk * 8);
    }
    bf16x8 vb[2];
    #pragma unroll
    for (int di = 0; di < 2; ++di) {
      #pragma unroll
      for (int j = 0; j < 8; ++j) {
        int k = ks * 32 + g * 8 + j;
        int chv = ((di * 2 + (c >> 3)) ^ g);
        vb[di][j] = Lh[4096 + k * 32 + chv * 8 + (c & 7)];
      }
    }
    #pragma unroll
    for (int qi = 0; qi < 4; ++qi)
      #pragma unroll
      for (int di = 0; di < 2; ++di)
        acc2[qi][di] = __builtin_amdgcn_mfma_f32_16x16x32_bf16(pa[qi], vb[di], acc2[qi][di], 0, 0, 0);
  }

  #pragma unroll
  for (int qi = 0; qi < 4; ++qi) {
    #pragma unroll
    for (int r = 0; r < 4; ++r) {
      int q = qi * 16 + g * 4 + r;
      if (q < 54) {
        __hip_bfloat16* orow = attn_out + (size_t)(li * 54 + q) * 128 + h * 32;
        #pragma unroll
        for (int di = 0; di < 2; ++di)
          orow[di * 16 + c] = __float2bfloat16(acc2[qi][di][r]);
      }
    }
  }
}

// ---------------------------------------------------------------------------
// Prompt mean over windows + residual
// ---------------------------------------------------------------------------
__global__ __launch_bounds__(128) void prompt_reduce(const float* __restrict__ x,
    const float* __restrict__ pbuf, float* __restrict__ out)
{
  int bp = blockIdx.x;
  int b = bp / 5, p = bp % 5;
  int c = threadIdx.x;
  float s = 0.f;
  for (int w = 0; w < 64; ++w)
    s += pbuf[((size_t)(w * 64 + b) * 5 + p) * 128 + c];
  size_t oidx = ((size_t)b * 3141 + p) * 128 + c;
  out[oidx] = x[oidx] + s * (1.f / 64.f);
}

// ---------------------------------------------------------------------------
// Fused MLP: out = x + fc2(gelu(fc1(LN2(x)))).  64 rows/block, 4 waves.
// h/xn swizzle uses swapnib(row&15) so the fragment write rows {r,4+r,8+r,12+r}
// land on distinct banks (writes free) and reads stay 2-way (free).
// GELU: tanh-form via exp2 + rcp (|t| small; error << bf16 rounding of h).
// ---------------------------------------------------------------------------
__global__ __launch_bounds__(256, 2) void mlp_fused(
    const float* __restrict__ xin,
    const float* __restrict__ gamma, const float* __restrict__ beta,
    const __hip_bfloat16* __restrict__ w1t, const float* __restrict__ b1,
    const __hip_bfloat16* __restrict__ w2t, const float* __restrict__ b2,
    float* __restrict__ outp)
{
  __shared__ short lds[32768];
  short* xn = lds;
  short* hb = lds + 8192;
  short* wb = lds + 16384;
  const int tid = threadIdx.x;
  const int wv = tid >> 6, lane = tid & 63;
  const int c = lane & 15, g = lane >> 4;
  const int r0 = blockIdx.x * 64;

  // ---- LN2: wave wv handles rows wv*16..+15
  for (int rr = 0; rr < 16; ++rr) {
    int row = wv * 16 + rr;
    const float* xr = xin + (size_t)(r0 + row) * 128;
    float v0 = xr[lane], v1 = xr[lane + 64];
    float s = v0 + v1, s2 = v0 * v0 + v1 * v1;
    #pragma unroll
    for (int off = 32; off > 0; off >>= 1) {
      s  += __shfl_xor(s,  off);
      s2 += __shfl_xor(s2, off);
    }
    float mu = s * (1.f / 128.f);
    float var = s2 * (1.f / 128.f) - mu * mu;
    float rs = rsqrtf(var + 1e-5f);
    float y0 = (v0 - mu) * rs * gamma[lane]      + beta[lane];
    float y1 = (v1 - mu) * rs * gamma[lane + 64] + beta[lane + 64];
    int sn = swapnib(row & 15);
    int na = lane, nbb = lane + 64;
    xn[row * 128 + (((na  >> 3) ^ sn) << 3) + (na  & 7)] = (short)f2b(y0);
    xn[row * 128 + (((nbb >> 3) ^ sn) << 3) + (nbb & 7)] = (short)f2b(y1);
  }
  __syncthreads();

  f32x4 acc2[4][2] = {};
  for (int s = 0; s < 4; ++s) {
    // ---- stage w1 strip s -> wb (128 rows x 128 k)
    #pragma unroll
    for (int p = 0; p < 8; ++p) {
      int wrow = p * 16 + wv * 4 + (lane >> 4);
      int ch = (lane & 15) ^ (wrow & 7);
      const __hip_bfloat16* ga = w1t + (size_t)(s * 128 + wrow) * 128 + ch * 8;
      __builtin_amdgcn_global_load_lds(
          (const __attribute__((address_space(1))) void*)ga,
          (__attribute__((address_space(3))) void*)(wb + p * 2048 + wv * 512),
          16, 0, 0);
    }
    __syncthreads();
    // ---- fc1: acc1 = xn @ w1s^T
    f32x4 acc1[4][2] = {};
    #pragma unroll
    for (int ks = 0; ks < 4; ++ks) {
      bf16x8 af[4], bf[2];
      #pragma unroll
      for (int mi = 0; mi < 4; ++mi) {
        int row = mi * 16 + c;
        af[mi] = *(const bf16x8*)(xn + row * 128 + (((ks * 4 + g) ^ swapnib(row & 15)) << 3));
      }
      #pragma unroll
      for (int ni = 0; ni < 2; ++ni) {
        int wrow = wv * 32 + ni * 16 + c;
        bf[ni] = *(const bf16x8*)(wb + wrow * 128 + (((ks * 4 + g) ^ (wrow & 7)) << 3));
      }
      #pragma unroll
      for (int mi = 0; mi < 4; ++mi)
        #pragma unroll
        for (int ni = 0; ni < 2; ++ni)
          acc1[mi][ni] = __builtin_amdgcn_mfma_f32_16x16x32_bf16(
              af[mi], bf[ni], acc1[mi][ni], 0, 0, 0);
    }
    // ---- fast GELU + write h (bf16, swapnib swizzle -> conflict-free)
    #pragma unroll
    for (int ni = 0; ni < 2; ++ni) {
      int col = wv * 32 + ni * 16 + c;
      float bv = b1[s * 128 + col];
      #pragma unroll
      for (int mi = 0; mi < 4; ++mi) {
        #pragma unroll
        for (int r = 0; r < 4; ++r) {
          int row = mi * 16 + g * 4 + r;
          float t = acc1[mi][ni][r] + bv;
          // gelu(t) = t * sigmoid(2u), u = sqrt(2/pi)*(t + 0.044715 t^3)
          float u = t * (0.7978845608028654f + 0.0356774081f * t * t);
          float e = exp2f(-2.8853900817779268f * u);
          t = t * __builtin_amdgcn_rcpf(1.0f + e);
          hb[row * 128 + (((col >> 3) ^ swapnib(row & 15)) << 3) + (col & 7)] = (short)f2b(t);
        }
      }
    }
    __syncthreads();
    // ---- stage w2 strip -> wb (128 out-cols x 128 k)
    #pragma unroll
    for (int p = 0; p < 8; ++p) {
      int wrow = p * 16 + wv * 4 + (lane >> 4);
      int ch = (lane & 15) ^ (wrow & 7);
      const __hip_bfloat16* ga = w2t + (size_t)wrow * 512 + s * 128 + ch * 8;
      __builtin_amdgcn_global_load_lds(
          (const __attribute__((address_space(1))) void*)ga,
          (__attribute__((address_space(3))) void*)(wb + p * 2048 + wv * 512),
          16, 0, 0);
    }
    __syncthreads();
    // ---- fc2: acc2 += h @ w2s^T
    #pragma unroll
    for (int ks = 0; ks < 4; ++ks) {
      bf16x8 af[4], bf[2];
      #pragma unroll
      for (int mi = 0; mi < 4; ++mi) {
        int row = mi * 16 + c;
        af[mi] = *(const bf16x8*)(hb + row * 128 + (((ks * 4 + g) ^ swapnib(row & 15)) << 3));
      }
      #pragma unroll
      for (int ni = 0; ni < 2; ++ni) {
        int wrow = wv * 32 + ni * 16 + c;
        bf[ni] = *(const bf16x8*)(wb + wrow * 128 + (((ks * 4 + g) ^ (wrow & 7)) << 3));
      }
      #pragma unroll
      for (int mi = 0; mi < 4; ++mi)
        #pragma unroll
        for (int ni = 0; ni < 2; ++ni)
          acc2[mi][ni] = __builtin_amdgcn_mfma_f32_16x16x32_bf16(
              af[mi], bf[ni], acc2[mi][ni], 0, 0, 0);
    }
    __syncthreads();
  }

  // ---- epilogue: out = acc2 + b2 + x
  #pragma unroll
  for (int mi = 0; mi < 4; ++mi) {
    #pragma unroll
    for (int r = 0; r < 4; ++r) {
      int row = r0 + mi * 16 + g * 4 + r;
      #pragma unroll
      for (int ni = 0; ni < 2; ++ni) {
        int col = wv * 32 + ni * 16 + c;
        size_t o = (size_t)row * 128 + col;
        outp[o] = acc2[mi][ni][r] + b2[col] + xin[o];
      }
    }
  }
}

// ---------------------------------------------------------------------------
// Launch
// ---------------------------------------------------------------------------
extern "C" void kernel_launch(void* const* d_in, const int* in_sizes, int n_in,
                              void* d_out, int out_size, void* d_ws, size_t ws_size,
                              hipStream_t stream) {
  const float* x      = (const float*)d_in[0];
  const float* n1g    = (const float*)d_in[1];
  const float* n1b    = (const float*)d_in[2];
  const float* qkv_w  = (const float*)d_in[3];
  const float* qkv_b  = (const float*)d_in[4];
  const float* proj_w = (const float*)d_in[5];
  const float* proj_b = (const float*)d_in[6];
  const float* rpb    = (const float*)d_in[7];
  const float* n2g    = (const float*)d_in[8];
  const float* n2b    = (const float*)d_in[9];
  const float* fc1w   = (const float*)d_in[10];
  const float* fc1b   = (const float*)d_in[11];
  const float* fc2w   = (const float*)d_in[12];
  const float* fc2b   = (const float*)d_in[13];
  float* out = (float*)d_out;
  char* ws = (char*)d_ws;

  __hip_bfloat16* wbuf = (__hip_bfloat16*)ws;
  __hip_bfloat16* w_qkv = wbuf;
  __hip_bfloat16* w_prj = wbuf + 49152;
  __hip_bfloat16* w_fc1 = wbuf + 65536;
  __hip_bfloat16* w_fc2 = wbuf + 131072;
  __hip_bfloat16* bias_tab = (__hip_bfloat16*)(ws + 393216);
  float* pbuf = (float*)(ws + 2490368);
  const size_t CHUNK_BASE = 12976128ULL;

  hipLaunchKernelGGL(convert_wt, dim3(192), dim3(256), 0, stream, qkv_w, w_qkv, 128, 384);
  hipLaunchKernelGGL(convert_wt, dim3(64),  dim3(256), 0, stream, proj_w, w_prj, 128, 128);
  hipLaunchKernelGGL(convert_wt, dim3(256), dim3(256), 0, stream, fc1w,  w_fc1, 128, 512);
  hipLaunchKernelGGL(convert_wt, dim3(256), dim3(256), 0, stream, fc2w,  w_fc2, 512, 128);
  hipLaunchKernelGGL(bias_gen, dim3(256), dim3(256), 0, stream, rpb, bias_tab);

  // ---- Phase 1: LN1 -> QKV -> attn(MFMA) -> proj(+scatter fused)
  int cw = 2048;
  while (cw > 64 && CHUNK_BASE + (size_t)cw * 54 * 1024 + 8192 > ws_size) cw >>= 1;
  {
    size_t R = (size_t)cw * 54;
    __hip_bfloat16* xw_c  = (__hip_bfloat16*)(ws + CHUNK_BASE);
    __hip_bfloat16* qkv_c = (__hip_bfloat16*)(ws + CHUNK_BASE + R * 256);
    for (int i0 = 0; i0 < 4096; i0 += cw) {
      int nr = cw * 54;
      hipLaunchKernelGGL(ln1_gather, dim3((nr + 3) / 4), dim3(256), 0, stream,
                         x, n1g, n1b, xw_c, i0, nr);
      hipLaunchKernelGGL((gemm_mfma<0, 1>), dim3(3, nr / 128), dim3(256), 0, stream,
                         xw_c, w_qkv, qkv_b, qkv_c, (const float*)nullptr,
                         (float*)nullptr, 0, nr, 384, 128);
      hipLaunchKernelGGL(attn_mfma, dim3(cw), dim3(256), 0, stream,
                         qkv_c, bias_tab, xw_c, i0);
      hipLaunchKernelGGL((gemm_mfma<3, 0>), dim3(1, nr / 128), dim3(256), 0, stream,
                         xw_c, w_prj, proj_b, (void*)out, x, pbuf, i0, nr, 128, 128);
    }
    hipLaunchKernelGGL(prompt_reduce, dim3(320), dim3(128), 0, stream, x, pbuf, out);
  }

  // ---- Phase 2: fused MLP (in-place on out), 201024 = 3141*64 rows
  hipLaunchKernelGGL(mlp_fused, dim3(3141), dim3(256), 0, stream,
                     out, n2g, n2b, w_fc1, fc1b, w_fc2, fc2b, out);
  (void)in_sizes; (void)n_in; (void)out_size; (void)ws_size;
}